// Round 2
// baseline (53973.029 us; speedup 1.0000x reference)
//
#include <hip/hip_runtime.h>
#include <hip/hip_bf16.h>

#define TT 500
#define BB 64
#define KSZ 128
#define VSZ 128
#define HH 512
#define EE 256
#define VOC 4096
#define LL 250
#define NBLK 256

// ws layout (floats)
#define WS_BAR   0
#define WS_XT0   512
#define WS_XT1   (512 + 40960)
#define WS_H2T0  (512 + 81920)
#define WS_H2T1  (512 + 90112)
#define WS_H2CTX (512 + 98304)
#define WS_INIT_END 98816

__device__ __forceinline__ float sigm(float x) { return 1.0f / (1.0f + __expf(-x)); }

// ---------------------------------------------------------------------------
// init: zero bar + state buffers; xT0 ctx part = values[t=0] (transposed)
// ---------------------------------------------------------------------------
__global__ __launch_bounds__(512) void k_init(const float* __restrict__ values,
                                              float* __restrict__ ws) {
    int i = blockIdx.x * 512 + threadIdx.x;
    if (i >= WS_INIT_END) return;
    float v = 0.0f;
    if (i >= WS_XT0 && i < WS_XT0 + 8192) {
        int i0 = i - WS_XT0;                 // k*64 + b, k<128
        v = values[(i0 & 63) * VSZ + (i0 >> 6)];
    }
    ws[i] = v;
}

// ---------------------------------------------------------------------------
// fp32 GEMM (K=256): C[m][n] = A[m][:256] . B[n][:256] + bias1[n] (+bias2[n])
// 64x64 tile, 256 threads, 4x4 per thread.
// ---------------------------------------------------------------------------
__global__ __launch_bounds__(256) void k_gemm_tn(
        const float* __restrict__ A, int lda,
        const float* __restrict__ B, int ldb,
        const float* __restrict__ bias1, const float* __restrict__ bias2,
        float* __restrict__ C, int ldc) {
    const int tid = threadIdx.x;
    const int m0 = blockIdx.y * 64, n0 = blockIdx.x * 64;
    const int tx = tid & 15, ty = tid >> 4;
    const int lm = tid >> 2, lk = (tid & 3) * 8;

    __shared__ float As[32][68];
    __shared__ float Bs[32][68];

    float c[4][4] = {{0.f}};

    for (int kb = 0; kb < 256; kb += 32) {
        const float* ap = A + (size_t)(m0 + lm) * lda + kb + lk;
        const float* bp = B + (size_t)(n0 + lm) * ldb + kb + lk;
        float4 a0 = *(const float4*)(ap);
        float4 a1 = *(const float4*)(ap + 4);
        float4 b0 = *(const float4*)(bp);
        float4 b1 = *(const float4*)(bp + 4);
        __syncthreads();
        As[lk + 0][lm] = a0.x; As[lk + 1][lm] = a0.y; As[lk + 2][lm] = a0.z; As[lk + 3][lm] = a0.w;
        As[lk + 4][lm] = a1.x; As[lk + 5][lm] = a1.y; As[lk + 6][lm] = a1.z; As[lk + 7][lm] = a1.w;
        Bs[lk + 0][lm] = b0.x; Bs[lk + 1][lm] = b0.y; Bs[lk + 2][lm] = b0.z; Bs[lk + 3][lm] = b0.w;
        Bs[lk + 4][lm] = b1.x; Bs[lk + 5][lm] = b1.y; Bs[lk + 6][lm] = b1.z; Bs[lk + 7][lm] = b1.w;
        __syncthreads();
#pragma unroll
        for (int kk = 0; kk < 32; ++kk) {
            const float4 a = *(const float4*)&As[kk][ty * 4];
            const float4 b = *(const float4*)&Bs[kk][tx * 4];
            c[0][0] += a.x * b.x; c[0][1] += a.x * b.y; c[0][2] += a.x * b.z; c[0][3] += a.x * b.w;
            c[1][0] += a.y * b.x; c[1][1] += a.y * b.y; c[1][2] += a.y * b.z; c[1][3] += a.y * b.w;
            c[2][0] += a.z * b.x; c[2][1] += a.z * b.y; c[2][2] += a.z * b.z; c[2][3] += a.z * b.w;
            c[3][0] += a.w * b.x; c[3][1] += a.w * b.y; c[3][2] += a.w * b.z; c[3][3] += a.w * b.w;
        }
    }

    const int n = n0 + tx * 4;
    float4 bb = *(const float4*)&bias1[n];
    if (bias2) {
        float4 b2 = *(const float4*)&bias2[n];
        bb.x += b2.x; bb.y += b2.y; bb.z += b2.z; bb.w += b2.w;
    }
#pragma unroll
    for (int i = 0; i < 4; ++i) {
        float4 r;
        r.x = c[i][0] + bb.x; r.y = c[i][1] + bb.y; r.z = c[i][2] + bb.z; r.w = c[i][3] + bb.w;
        *(float4*)&C[(size_t)(m0 + ty * 4 + i) * ldc + n] = r;
    }
}

// ---------------------------------------------------------------------------
// two-level grid barrier (16 groups of 16 blocks); state in ws uints:
//   gen @ u[0], master cnt @ u[8], group g cnt @ u[16 + g*16]
// ---------------------------------------------------------------------------
__device__ __forceinline__ void gridbar(unsigned* bar) {
    __syncthreads();
    if (threadIdx.x == 0) {
        unsigned* gen  = bar;
        unsigned* mcnt = bar + 8;
        unsigned* cnt  = bar + 16 + ((blockIdx.x >> 4) << 4);
        unsigned g = __hip_atomic_load(gen, __ATOMIC_RELAXED, __HIP_MEMORY_SCOPE_AGENT);
        __threadfence();  // release prior writes
        unsigned a = __hip_atomic_fetch_add(cnt, 1u, __ATOMIC_ACQ_REL, __HIP_MEMORY_SCOPE_AGENT);
        if (a == 15u) {
            __hip_atomic_store(cnt, 0u, __ATOMIC_RELAXED, __HIP_MEMORY_SCOPE_AGENT);
            unsigned ma = __hip_atomic_fetch_add(mcnt, 1u, __ATOMIC_ACQ_REL, __HIP_MEMORY_SCOPE_AGENT);
            if (ma == 15u) {
                __hip_atomic_store(mcnt, 0u, __ATOMIC_RELAXED, __HIP_MEMORY_SCOPE_AGENT);
                __hip_atomic_store(gen, g + 1u, __ATOMIC_RELEASE, __HIP_MEMORY_SCOPE_AGENT);
            }
        }
        while (__hip_atomic_load(gen, __ATOMIC_ACQUIRE, __HIP_MEMORY_SCOPE_AGENT) == g)
            __builtin_amdgcn_s_sleep(1);
        __threadfence();  // acquire side
    }
    __syncthreads();
}

// ---------------------------------------------------------------------------
// Persistent kernel: 250 decoder steps. 256 blocks x 512 threads.
// Roles: all blocks -> LSTM1 (2 h rows each); blk<128 -> LSTM2 (1 r each);
//        blk<64 -> attention (1 b each).
// Weights cached in LDS once; c1/c2 in registers for the whole loop.
// ---------------------------------------------------------------------------
__global__ __launch_bounds__(512) void k_loop(
        const float* __restrict__ key, const float* __restrict__ values,
        const int* __restrict__ speech_len, const int* __restrict__ text,
        const float* __restrict__ EmbW,
        const float* __restrict__ w_ih1, const float* __restrict__ w_hh1,
        const float* __restrict__ w_ih2, const float* __restrict__ b_ih2,
        const float* __restrict__ w_hh2, const float* __restrict__ b_hh2,
        float* __restrict__ ws) {
    const int blk = blockIdx.x;
    const int tid = threadIdx.x;

    unsigned* bar = (unsigned*)ws;
    float* xTb[2]  = { ws + WS_XT0, ws + WS_XT1 };
    float* h2Tb[2] = { ws + WS_H2T0, ws + WS_H2T1 };
    float* h2ctx   = ws + WS_H2CTX;

    __shared__ float sW1[2][4][640];     // lstm1 combined rows [ctx(128);h1(512)]
    __shared__ float sW2[4][640];        // lstm2 combined rows [h1(512);h2(128)]
    __shared__ float sB2[4];
    __shared__ float red3[3][2][4][64];
    __shared__ float part2[7][4][64];
    __shared__ float h2s[128];
    __shared__ float sc[TT];
    __shared__ float rr[512];

    const int h0 = blk * 2;
    // preload lstm1 weights (combined k-layout)
#pragma unroll
    for (int row = 0; row < 8; ++row) {
        int hl = row >> 2, g = row & 3;
        int j = g * 512 + h0 + hl;
        for (int k = tid; k < 640; k += 512)
            sW1[hl][g][k] = (k < 128) ? w_ih1[j * 384 + 256 + k]
                                      : w_hh1[j * 512 + k - 128];
    }
    if (blk < 128) {
#pragma unroll
        for (int g = 0; g < 4; ++g) {
            int j = g * 128 + blk;
            for (int k = tid; k < 640; k += 512)
                sW2[g][k] = (k < 512) ? w_ih2[j * 512 + k]
                                      : w_hh2[j * 128 + k - 512];
        }
        if (tid < 4) sB2[tid] = b_ih2[tid * 128 + blk] + b_hh2[tid * 128 + blk];
    }
    __syncthreads();

    float c1 = 0.f, c2 = 0.f;

    for (int l = 0; l < LL; ++l) {
        const float* xcur  = xTb[l & 1];
        float*       xnext = xTb[(l & 1) ^ 1];
        const float* h2cur = h2Tb[l & 1];
        float*       h2next= h2Tb[(l & 1) ^ 1];

        // ---------------- phase A: LSTM1 ----------------
        {
            const int b = tid & 63;
            const int q = tid >> 6;          // 0..7
            const int hl = q & 1, ks = q >> 1;  // ks 0..3, 160 k each
            float a0, a1, a2, a3;
            if (ks == 0) {
                int tok = (l == 0) ? 0 : text[b * LL + l - 1];
                const float* er = EmbW + (size_t)tok * 2048;
                int h = h0 + hl;
                a0 = er[h]; a1 = er[512 + h]; a2 = er[1024 + h]; a3 = er[1536 + h];
            } else { a0 = a1 = a2 = a3 = 0.f; }
            const int ka = ks * 160;
            const float* xk = xcur + b + (ka << 6);
#pragma unroll 4
            for (int c = 0; c < 40; ++c) {
                const int k = ka + c * 4;
                float x0 = xk[0], x1 = xk[64], x2 = xk[128], x3 = xk[192];
                float4 w;
                w = *(const float4*)&sW1[hl][0][k]; a0 += w.x*x0 + w.y*x1 + w.z*x2 + w.w*x3;
                w = *(const float4*)&sW1[hl][1][k]; a1 += w.x*x0 + w.y*x1 + w.z*x2 + w.w*x3;
                w = *(const float4*)&sW1[hl][2][k]; a2 += w.x*x0 + w.y*x1 + w.z*x2 + w.w*x3;
                w = *(const float4*)&sW1[hl][3][k]; a3 += w.x*x0 + w.y*x1 + w.z*x2 + w.w*x3;
                xk += 256;
            }
            if (ks) {
                red3[ks - 1][hl][0][b] = a0; red3[ks - 1][hl][1][b] = a1;
                red3[ks - 1][hl][2][b] = a2; red3[ks - 1][hl][3][b] = a3;
            }
            __syncthreads();
            if (ks == 0) {
                a0 += red3[0][hl][0][b] + red3[1][hl][0][b] + red3[2][hl][0][b];
                a1 += red3[0][hl][1][b] + red3[1][hl][1][b] + red3[2][hl][1][b];
                a2 += red3[0][hl][2][b] + red3[1][hl][2][b] + red3[2][hl][2][b];
                a3 += red3[0][hl][3][b] + red3[1][hl][3][b] + red3[2][hl][3][b];
                float iv = sigm(a0), fv = sigm(a1), gv = tanhf(a2), ov = sigm(a3);
                c1 = fv * c1 + iv * gv;
                xnext[(128 + h0 + hl) * 64 + b] = ov * tanhf(c1);
            }
        }
        gridbar(bar);

        // ---------------- phase B: LSTM2 ----------------
        if (blk < 128) {
            const int b = tid & 63;
            const int ks = tid >> 6;          // 0..7, 80 k each
            float a0, a1, a2, a3;
            if (ks == 0) { a0 = sB2[0]; a1 = sB2[1]; a2 = sB2[2]; a3 = sB2[3]; }
            else { a0 = a1 = a2 = a3 = 0.f; }
            const float* h1p = xnext + 128 * 64 + b;
            const float* h2p = h2cur + b;
            const int ka = ks * 80;
#pragma unroll 4
            for (int c = 0; c < 20; ++c) {
                const int k = ka + c * 4;
                const float* src = (k < 512) ? (h1p + (k << 6)) : (h2p + ((k - 512) << 6));
                float x0 = src[0], x1 = src[64], x2 = src[128], x3 = src[192];
                float4 w;
                w = *(const float4*)&sW2[0][k]; a0 += w.x*x0 + w.y*x1 + w.z*x2 + w.w*x3;
                w = *(const float4*)&sW2[1][k]; a1 += w.x*x0 + w.y*x1 + w.z*x2 + w.w*x3;
                w = *(const float4*)&sW2[2][k]; a2 += w.x*x0 + w.y*x1 + w.z*x2 + w.w*x3;
                w = *(const float4*)&sW2[3][k]; a3 += w.x*x0 + w.y*x1 + w.z*x2 + w.w*x3;
            }
            if (ks) {
                part2[ks - 1][0][b] = a0; part2[ks - 1][1][b] = a1;
                part2[ks - 1][2][b] = a2; part2[ks - 1][3][b] = a3;
            }
            __syncthreads();
            if (ks == 0) {
#pragma unroll
                for (int p = 0; p < 7; ++p) {
                    a0 += part2[p][0][b]; a1 += part2[p][1][b];
                    a2 += part2[p][2][b]; a3 += part2[p][3][b];
                }
                float iv = sigm(a0), fv = sigm(a1), gv = tanhf(a2), ov = sigm(a3);
                c2 = fv * c2 + iv * gv;
                float h2v = ov * tanhf(c2);
                h2next[blk * 64 + b] = h2v;
                h2ctx[((size_t)b * LL + l) * 256 + blk] = h2v;
            }
        }
        gridbar(bar);

        // ---------------- phase C: attention ----------------
        if (blk < 64) {
            const int b = blk;
            if (tid < 128) h2s[tid] = h2next[tid * 64 + b];
            __syncthreads();
            const int len = speech_len[b];
            float me = -1e30f;
            if (tid < TT) {
                const float* kr = key + ((size_t)tid * BB + b) * KSZ;
                float e = 0.f;
#pragma unroll 8
                for (int k = 0; k < KSZ; k += 4) {
                    float4 kv = *(const float4*)(kr + k);
                    e += kv.x * h2s[k] + kv.y * h2s[k+1] + kv.z * h2s[k+2] + kv.w * h2s[k+3];
                }
                me = (tid < len) ? e : 0.0f;
                sc[tid] = me;
            }
            rr[tid] = me;
            __syncthreads();
#pragma unroll
            for (int s = 256; s > 0; s >>= 1) {
                if (tid < s) rr[tid] = fmaxf(rr[tid], rr[tid + s]);
                __syncthreads();
            }
            const float m = rr[0];
            __syncthreads();
            float p = 0.f;
            if (tid < TT) { p = __expf(sc[tid] - m); sc[tid] = p; }
            rr[tid] = p;
            __syncthreads();
#pragma unroll
            for (int s = 256; s > 0; s >>= 1) {
                if (tid < s) rr[tid] += rr[tid + s];
                __syncthreads();
            }
            const float inv = 1.0f / rr[0];
            __syncthreads();
            const int v = tid & 127, qt = tid >> 7;
            float acc = 0.f;
            const float* vp = values + (size_t)b * VSZ + v;
#pragma unroll 4
            for (int t = qt * 125; t < qt * 125 + 125; ++t)
                acc += sc[t] * vp[(size_t)t * BB * VSZ];
            rr[tid] = acc;
            __syncthreads();
            if (tid < 128) {
                float ctx = (rr[tid] + rr[tid + 128] + rr[tid + 256] + rr[tid + 384]) * inv;
                xnext[tid * 64 + b] = ctx;
                h2ctx[((size_t)b * LL + l) * 256 + 128 + tid] = ctx;
            }
        }
        gridbar(bar);
    }
}

// ---------------------------------------------------------------------------
extern "C" void kernel_launch(void* const* d_in, const int* in_sizes, int n_in,
                              void* d_out, int out_size, void* d_ws, size_t ws_size,
                              hipStream_t stream) {
    const float* key        = (const float*)d_in[0];
    const float* values     = (const float*)d_in[1];
    const int*   speech_len = (const int*)d_in[2];
    const int*   text       = (const int*)d_in[3];
    const float* embedding  = (const float*)d_in[4];
    const float* w_ih1 = (const float*)d_in[5];
    const float* b_ih1 = (const float*)d_in[6];
    const float* w_hh1 = (const float*)d_in[7];
    const float* b_hh1 = (const float*)d_in[8];
    const float* w_ih2 = (const float*)d_in[9];
    const float* b_ih2 = (const float*)d_in[10];
    const float* w_hh2 = (const float*)d_in[11];
    const float* b_hh2 = (const float*)d_in[12];
    const float* w_out = (const float*)d_in[13];
    const float* b_out = (const float*)d_in[14];
    float* out = (float*)d_out;

    float* ws    = (float*)d_ws;
    float* h2ctx = ws + WS_H2CTX;
    float* EmbW  = out;  // 4096*2048 scratch at head of out; overwritten by final GEMM

    k_init<<<193, 512, 0, stream>>>(values, ws);
    // EmbW[v][j] = embedding[v] . w_ih1[j][:256] + b_ih1[j] + b_hh1[j]
    k_gemm_tn<<<dim3(32, 64), 256, 0, stream>>>(embedding, 256, w_ih1, 384,
                                                b_ih1, b_hh1, EmbW, 2048);
    k_loop<<<NBLK, 512, 0, stream>>>(key, values, speech_len, text, EmbW,
                                     w_ih1, w_hh1, w_ih2, b_ih2, w_hh2, b_hh2, ws);
    // out[b*250+l][v] = h2ctx[b*250+l] . w_out[v] + b_out[v]
    k_gemm_tn<<<dim3(64, 250), 256, 0, stream>>>(h2ctx, 256, w_out, 256,
                                                 b_out, nullptr, out, 4096);
}

// Round 3
// 16136.316 us; speedup vs baseline: 3.3448x; 3.3448x over previous
//
#include <hip/hip_runtime.h>
#include <hip/hip_bf16.h>

#define TT 500
#define BB 64
#define KSZ 128
#define VSZ 128
#define LL 250
#define NBLK 256

// ws float offsets
#define WS_BAR    0                         // 2048 floats (barrier state)
#define WS_E      2048                      // 64*512 energies
#define WS_XT0    (WS_E + 32768)            // 640*64 packed [k/4][b][4]
#define WS_XT1    (WS_XT0 + 40960)
#define WS_H2T0   (WS_XT1 + 40960)          // 128*64 packed
#define WS_H2T1   (WS_H2T0 + 8192)
#define WS_H2RM   (WS_H2T1 + 8192)          // 64*128 row-major h2
#define WS_H2CTX  (WS_H2RM + 8192)          // 16000*256
#define WS_INIT_END WS_H2CTX

__device__ __forceinline__ float sigm(float x) { return 1.0f / (1.0f + __expf(-x)); }

// ---------------------------------------------------------------------------
// init: zero bar/e/x/h2 buffers; xT0 ctx part = values[t=0] (k4-packed)
// ---------------------------------------------------------------------------
__global__ __launch_bounds__(512) void k_init(const float* __restrict__ values,
                                              float* __restrict__ ws) {
    int i = blockIdx.x * 512 + threadIdx.x;
    if (i >= WS_INIT_END) return;
    float v = 0.0f;
    if (i >= WS_XT0 && i < WS_XT0 + 8192) {
        int i0 = i - WS_XT0;                 // kk*256 + b*4 + j
        int kk = i0 >> 8, r = i0 & 255;
        int b = r >> 2, j = r & 3;
        v = values[b * VSZ + kk * 4 + j];
    }
    ws[i] = v;
}

// ---------------------------------------------------------------------------
// fp32 GEMM (K=256): C[m][n] = A[m][:256] . B[n][:256] + bias1[n] (+bias2[n])
// ---------------------------------------------------------------------------
__global__ __launch_bounds__(256) void k_gemm_tn(
        const float* __restrict__ A, int lda,
        const float* __restrict__ B, int ldb,
        const float* __restrict__ bias1, const float* __restrict__ bias2,
        float* __restrict__ C, int ldc) {
    const int tid = threadIdx.x;
    const int m0 = blockIdx.y * 64, n0 = blockIdx.x * 64;
    const int tx = tid & 15, ty = tid >> 4;
    const int lm = tid >> 2, lk = (tid & 3) * 8;

    __shared__ float As[32][68];
    __shared__ float Bs[32][68];

    float c[4][4] = {{0.f}};

    for (int kb = 0; kb < 256; kb += 32) {
        const float* ap = A + (size_t)(m0 + lm) * lda + kb + lk;
        const float* bp = B + (size_t)(n0 + lm) * ldb + kb + lk;
        float4 a0 = *(const float4*)(ap);
        float4 a1 = *(const float4*)(ap + 4);
        float4 b0 = *(const float4*)(bp);
        float4 b1 = *(const float4*)(bp + 4);
        __syncthreads();
        As[lk + 0][lm] = a0.x; As[lk + 1][lm] = a0.y; As[lk + 2][lm] = a0.z; As[lk + 3][lm] = a0.w;
        As[lk + 4][lm] = a1.x; As[lk + 5][lm] = a1.y; As[lk + 6][lm] = a1.z; As[lk + 7][lm] = a1.w;
        Bs[lk + 0][lm] = b0.x; Bs[lk + 1][lm] = b0.y; Bs[lk + 2][lm] = b0.z; Bs[lk + 3][lm] = b0.w;
        Bs[lk + 4][lm] = b1.x; Bs[lk + 5][lm] = b1.y; Bs[lk + 6][lm] = b1.z; Bs[lk + 7][lm] = b1.w;
        __syncthreads();
#pragma unroll
        for (int kk = 0; kk < 32; ++kk) {
            const float4 a = *(const float4*)&As[kk][ty * 4];
            const float4 b = *(const float4*)&Bs[kk][tx * 4];
            c[0][0] += a.x * b.x; c[0][1] += a.x * b.y; c[0][2] += a.x * b.z; c[0][3] += a.x * b.w;
            c[1][0] += a.y * b.x; c[1][1] += a.y * b.y; c[1][2] += a.y * b.z; c[1][3] += a.y * b.w;
            c[2][0] += a.z * b.x; c[2][1] += a.z * b.y; c[2][2] += a.z * b.z; c[2][3] += a.z * b.w;
            c[3][0] += a.w * b.x; c[3][1] += a.w * b.y; c[3][2] += a.w * b.z; c[3][3] += a.w * b.w;
        }
    }

    const int n = n0 + tx * 4;
    float4 bb = *(const float4*)&bias1[n];
    if (bias2) {
        float4 b2 = *(const float4*)&bias2[n];
        bb.x += b2.x; bb.y += b2.y; bb.z += b2.z; bb.w += b2.w;
    }
#pragma unroll
    for (int i = 0; i < 4; ++i) {
        float4 r;
        r.x = c[i][0] + bb.x; r.y = c[i][1] + bb.y; r.z = c[i][2] + bb.z; r.w = c[i][3] + bb.w;
        *(float4*)&C[(size_t)(m0 + ty * 4 + i) * ldc + n] = r;
    }
}

// ---------------------------------------------------------------------------
// grid barrier, monotonic counters, RELAXED spin (no per-iteration invalidate),
// exactly one release fence before arrive and one acquire fence after exit.
//   u[0]=gen, u[16]=master cnt, u[32+g*32]=group g cnt (16 groups of 16)
// ---------------------------------------------------------------------------
__device__ __forceinline__ void gridbar(unsigned* bar, unsigned bk, int blk) {
    __syncthreads();
    if (threadIdx.x == 0) {
        __builtin_amdgcn_fence(__ATOMIC_RELEASE, "agent");
        unsigned* cnt = bar + 32 + ((blk & 15) << 5);
        unsigned a = __hip_atomic_fetch_add(cnt, 1u, __ATOMIC_RELAXED, __HIP_MEMORY_SCOPE_AGENT);
        if (a == bk * 16u - 1u) {
            unsigned ma = __hip_atomic_fetch_add(bar + 16, 1u, __ATOMIC_RELAXED, __HIP_MEMORY_SCOPE_AGENT);
            if (ma == bk * 16u - 1u)
                __hip_atomic_store(bar, bk, __ATOMIC_RELAXED, __HIP_MEMORY_SCOPE_AGENT);
        }
        while (__hip_atomic_load(bar, __ATOMIC_RELAXED, __HIP_MEMORY_SCOPE_AGENT) < bk)
            __builtin_amdgcn_s_sleep(2);
        __builtin_amdgcn_fence(__ATOMIC_ACQUIRE, "agent");
    }
    __syncthreads();
}

// ---------------------------------------------------------------------------
// Persistent kernel: 250 steps, 256 blocks x 512 threads, 4 barriers/step.
// A: lstm1 (all blocks, 2 h rows); B: lstm2 (blk<128, 1 r);
// C1: energies (4 t-quarters per b); C2: softmax+context (4 v-quarters per b).
// Weights LDS-resident; c1/c2 in registers.
// ---------------------------------------------------------------------------
__global__ __launch_bounds__(512) void k_loop(
        const float* __restrict__ key, const float* __restrict__ values,
        const int* __restrict__ speech_len, const int* __restrict__ text,
        const float* __restrict__ EmbW,
        const float* __restrict__ w_ih1, const float* __restrict__ w_hh1,
        const float* __restrict__ w_ih2, const float* __restrict__ b_ih2,
        const float* __restrict__ w_hh2, const float* __restrict__ b_hh2,
        float* __restrict__ ws) {
    const int blk = blockIdx.x;
    const int tid = threadIdx.x;

    unsigned* bar = (unsigned*)ws;
    float* e_ws   = ws + WS_E;
    float* xTb[2]  = { ws + WS_XT0, ws + WS_XT1 };
    float* h2Tb[2] = { ws + WS_H2T0, ws + WS_H2T1 };
    float* h2rm    = ws + WS_H2RM;
    float* h2ctx   = ws + WS_H2CTX;

    __shared__ float sW1[2][4][640];
    __shared__ float sW2[4][640];
    __shared__ float sB2[4];
    __shared__ float red3[3][2][4][64];
    __shared__ float part2[7][4][64];
    __shared__ float h2s[128];
    __shared__ float sc[512];
    __shared__ float rr[512];
    __shared__ float red2[16][32];

    const int h0 = blk * 2;
#pragma unroll
    for (int row = 0; row < 8; ++row) {
        int hl = row >> 2, g = row & 3;
        int j = g * 512 + h0 + hl;
        for (int k = tid; k < 640; k += 512)
            sW1[hl][g][k] = (k < 128) ? w_ih1[j * 384 + 256 + k]
                                      : w_hh1[j * 512 + k - 128];
    }
    if (blk < 128) {
#pragma unroll
        for (int g = 0; g < 4; ++g) {
            int j = g * 128 + blk;
            for (int k = tid; k < 640; k += 512)
                sW2[g][k] = (k < 512) ? w_ih2[j * 512 + k]
                                      : w_hh2[j * 128 + k - 512];
        }
        if (tid < 4) sB2[tid] = b_ih2[tid * 128 + blk] + b_hh2[tid * 128 + blk];
    }
    __syncthreads();

    float c1 = 0.f, c2 = 0.f;
    unsigned bk = 0;

    for (int l = 0; l < LL; ++l) {
        const float* xcur  = xTb[l & 1];
        float*       xnext = xTb[(l & 1) ^ 1];
        const float* h2cur = h2Tb[l & 1];
        float*       h2next= h2Tb[(l & 1) ^ 1];

        // ---------------- phase A: LSTM1 ----------------
        {
            const int b = tid & 63;
            const int q = tid >> 6;             // 0..7
            const int hl = q & 1, ks = q >> 1;  // ks 0..3 (40 packed kk each)
            float a0, a1, a2, a3;
            if (ks == 0) {
                int tok = (l == 0) ? 0 : text[b * LL + l - 1];
                const float* er = EmbW + (size_t)tok * 2048;
                int h = h0 + hl;
                a0 = er[h]; a1 = er[512 + h]; a2 = er[1024 + h]; a3 = er[1536 + h];
            } else { a0 = a1 = a2 = a3 = 0.f; }
            const float4* x4 = (const float4*)xcur + b;
            const int kk0 = ks * 40;
#pragma unroll 4
            for (int kk = kk0; kk < kk0 + 40; ++kk) {
                float4 xv = x4[kk * 64];
                float4 w;
                w = *(const float4*)&sW1[hl][0][kk * 4]; a0 += w.x*xv.x + w.y*xv.y + w.z*xv.z + w.w*xv.w;
                w = *(const float4*)&sW1[hl][1][kk * 4]; a1 += w.x*xv.x + w.y*xv.y + w.z*xv.z + w.w*xv.w;
                w = *(const float4*)&sW1[hl][2][kk * 4]; a2 += w.x*xv.x + w.y*xv.y + w.z*xv.z + w.w*xv.w;
                w = *(const float4*)&sW1[hl][3][kk * 4]; a3 += w.x*xv.x + w.y*xv.y + w.z*xv.z + w.w*xv.w;
            }
            if (ks) {
                red3[ks - 1][hl][0][b] = a0; red3[ks - 1][hl][1][b] = a1;
                red3[ks - 1][hl][2][b] = a2; red3[ks - 1][hl][3][b] = a3;
            }
            __syncthreads();
            if (ks == 0) {
                a0 += red3[0][hl][0][b] + red3[1][hl][0][b] + red3[2][hl][0][b];
                a1 += red3[0][hl][1][b] + red3[1][hl][1][b] + red3[2][hl][1][b];
                a2 += red3[0][hl][2][b] + red3[1][hl][2][b] + red3[2][hl][2][b];
                a3 += red3[0][hl][3][b] + red3[1][hl][3][b] + red3[2][hl][3][b];
                float iv = sigm(a0), fv = sigm(a1), gv = tanhf(a2), ov = sigm(a3);
                c1 = fv * c1 + iv * gv;
                float h1v = ov * tanhf(c1);
                const int k = 128 + h0 + hl;
                xnext[(k >> 2) * 256 + b * 4 + (k & 3)] = h1v;
            }
        }
        ++bk; gridbar(bar, bk, blk);

        // ---------------- phase B: LSTM2 ----------------
        if (blk < 128) {
            const int b = tid & 63;
            const int ks = tid >> 6;            // 0..7 (20 packed kk each)
            const int r = blk;
            float a0, a1, a2, a3;
            if (ks == 0) { a0 = sB2[0]; a1 = sB2[1]; a2 = sB2[2]; a3 = sB2[3]; }
            else { a0 = a1 = a2 = a3 = 0.f; }
            const float4* h1p = (const float4*)xnext + 32 * 64 + b;
            const float4* h2p = (const float4*)h2cur + b;
            const int kk0 = ks * 20;
#pragma unroll 4
            for (int kk = kk0; kk < kk0 + 20; ++kk) {
                float4 xv = (kk < 128) ? h1p[kk * 64] : h2p[(kk - 128) * 64];
                float4 w;
                w = *(const float4*)&sW2[0][kk * 4]; a0 += w.x*xv.x + w.y*xv.y + w.z*xv.z + w.w*xv.w;
                w = *(const float4*)&sW2[1][kk * 4]; a1 += w.x*xv.x + w.y*xv.y + w.z*xv.z + w.w*xv.w;
                w = *(const float4*)&sW2[2][kk * 4]; a2 += w.x*xv.x + w.y*xv.y + w.z*xv.z + w.w*xv.w;
                w = *(const float4*)&sW2[3][kk * 4]; a3 += w.x*xv.x + w.y*xv.y + w.z*xv.z + w.w*xv.w;
            }
            if (ks) {
                part2[ks - 1][0][b] = a0; part2[ks - 1][1][b] = a1;
                part2[ks - 1][2][b] = a2; part2[ks - 1][3][b] = a3;
            }
            __syncthreads();
            if (ks == 0) {
#pragma unroll
                for (int p = 0; p < 7; ++p) {
                    a0 += part2[p][0][b]; a1 += part2[p][1][b];
                    a2 += part2[p][2][b]; a3 += part2[p][3][b];
                }
                float iv = sigm(a0), fv = sigm(a1), gv = tanhf(a2), ov = sigm(a3);
                c2 = fv * c2 + iv * gv;
                float h2v = ov * tanhf(c2);
                h2next[(r >> 2) * 256 + b * 4 + (r & 3)] = h2v;
                h2rm[b * 128 + r] = h2v;
                h2ctx[((size_t)b * LL + l) * 256 + r] = h2v;
            }
        }
        ++bk; gridbar(bar, bk, blk);

        // ---------------- phase C1: energies ----------------
        {
            const int b  = blk >> 2;
            const int tq = blk & 3;
            if (tid < 128) h2s[tid] = h2rm[b * 128 + tid];
            __syncthreads();
            const int tl = tid >> 2, kq = tid & 3;
            if (tl < 125) {
                const int t = tq * 125 + tl;
                const float4* kr = (const float4*)(key + ((size_t)t * BB + b) * KSZ) + kq * 8;
                const float4* hh = (const float4*)h2s + kq * 8;
                float e = 0.f;
#pragma unroll
                for (int i = 0; i < 8; ++i) {
                    float4 kv = kr[i]; float4 hv = hh[i];
                    e += kv.x*hv.x + kv.y*hv.y + kv.z*hv.z + kv.w*hv.w;
                }
                e += __shfl_xor(e, 1);
                e += __shfl_xor(e, 2);
                if (kq == 0) {
                    const int len = speech_len[b];
                    e_ws[b * 512 + t] = (t < len) ? e : 0.0f;
                }
            }
        }
        ++bk; gridbar(bar, bk, blk);

        // ---------------- phase C2: softmax + context ----------------
        {
            const int b  = blk >> 2;
            const int vq = blk & 3;
            float me = -1e30f;
            if (tid < TT) me = e_ws[b * 512 + tid];
            rr[tid] = me;
            __syncthreads();
#pragma unroll
            for (int s = 256; s > 0; s >>= 1) {
                if (tid < s) rr[tid] = fmaxf(rr[tid], rr[tid + s]);
                __syncthreads();
            }
            const float m = rr[0];
            __syncthreads();
            float p = 0.f;
            if (tid < TT) p = __expf(me - m);
            sc[tid] = p;
            rr[tid] = p;
            __syncthreads();
#pragma unroll
            for (int s = 256; s > 0; s >>= 1) {
                if (tid < s) rr[tid] += rr[tid + s];
                __syncthreads();
            }
            const float inv = 1.0f / rr[0];
            __syncthreads();
            const int v = tid & 31, tg = tid >> 5;
            float acc = 0.f;
            const float* vp = values + (size_t)b * VSZ + vq * 32 + v;
            for (int t = tg; t < TT; t += 16)
                acc += sc[t] * vp[(size_t)t * BB * VSZ];
            red2[tg][v] = acc;
            __syncthreads();
            if (tid < 32) {
                float s = 0.f;
#pragma unroll
                for (int g = 0; g < 16; ++g) s += red2[g][tid];
                float ctx = s * inv;
                const int k = vq * 32 + tid;
                xnext[(k >> 2) * 256 + b * 4 + (k & 3)] = ctx;
                h2ctx[((size_t)b * LL + l) * 256 + 128 + k] = ctx;
            }
        }
        ++bk; gridbar(bar, bk, blk);
    }
}

// ---------------------------------------------------------------------------
extern "C" void kernel_launch(void* const* d_in, const int* in_sizes, int n_in,
                              void* d_out, int out_size, void* d_ws, size_t ws_size,
                              hipStream_t stream) {
    const float* key        = (const float*)d_in[0];
    const float* values     = (const float*)d_in[1];
    const int*   speech_len = (const int*)d_in[2];
    const int*   text       = (const int*)d_in[3];
    const float* embedding  = (const float*)d_in[4];
    const float* w_ih1 = (const float*)d_in[5];
    const float* b_ih1 = (const float*)d_in[6];
    const float* w_hh1 = (const float*)d_in[7];
    const float* b_hh1 = (const float*)d_in[8];
    const float* w_ih2 = (const float*)d_in[9];
    const float* b_ih2 = (const float*)d_in[10];
    const float* w_hh2 = (const float*)d_in[11];
    const float* b_hh2 = (const float*)d_in[12];
    const float* w_out = (const float*)d_in[13];
    const float* b_out = (const float*)d_in[14];
    float* out = (float*)d_out;

    float* ws    = (float*)d_ws;
    float* h2ctx = ws + WS_H2CTX;
    float* EmbW  = out;  // 4096*2048 scratch at head of out; overwritten by final GEMM

    k_init<<<276, 512, 0, stream>>>(values, ws);
    // EmbW[v][j] = embedding[v] . w_ih1[j][:256] + b_ih1[j] + b_hh1[j]
    k_gemm_tn<<<dim3(32, 64), 256, 0, stream>>>(embedding, 256, w_ih1, 384,
                                                b_ih1, b_hh1, EmbW, 2048);
    k_loop<<<NBLK, 512, 0, stream>>>(key, values, speech_len, text, EmbW,
                                     w_ih1, w_hh1, w_ih2, b_ih2, w_hh2, b_hh2, ws);
    // out[b*250+l][v] = h2ctx[b*250+l] . w_out[v] + b_out[v]
    k_gemm_tn<<<dim3(64, 250), 256, 0, stream>>>(h2ctx, 256, w_out, 256,
                                                 b_out, nullptr, out, 4096);
}

// Round 4
// 12127.665 us; speedup vs baseline: 4.4504x; 1.3305x over previous
//
#include <hip/hip_runtime.h>
#include <hip/hip_bf16.h>

#define TT 500
#define BB 64
#define KSZ 128
#define VSZ 128
#define LL 250
#define NBLK 256

// ---- ws float offsets ----
#define WS_BAR    0                    // 1024 (barrier state, u32)
#define WS_XT0    1024                 // 160kk x 64b x4 packed (h1 at kk 32..159)
#define WS_XT1    (WS_XT0 + 40960)
#define WS_H2T0   (WS_XT1 + 40960)     // 32kk x 256
#define WS_H2T1   (WS_H2T0 + 8192)
#define WS_H2RM   (WS_H2T1 + 8192)     // 64 x 128 row-major h2
#define WS_ATTM   (WS_H2RM + 8192)     // [4][64] quarter max
#define WS_ATTS   (WS_ATTM + 256)      // [4][64] quarter sum
#define WS_ATTC   (WS_ATTS + 256)      // [4][32kk][64b][4] partial ctx
#define WS_H2CTX  (WS_ATTC + 32768)    // 16000 x 256
#define WS_INIT_END WS_H2CTX           // = 140800

// ---- k_loop dynamic LDS byte offsets ----
#define OFF_KEY 0                       // 125 x 136 fp32 (row pad 136)
#define OFF_VAL 68000                   // 125 x 128 bf16 (u32-paired)
#define OFF_W1  100000                  // 8 x 640 fp32
#define OFF_W2  120480                  // 4 x 640 fp32
#define OFF_RED 130720                  // 3584 fp32 (union: A-red / B-red / C1-red)
#define OFF_H2S 145056                  // 32 f4 @ stride 5 f4 (bank-spread) = 2560B
#define OFF_SC  147616                  // 128 fp32
#define OFF_SM  148128                  // 16 fp32 ([0]=max bcast, [4..7]=sB2)
#define LDS_BYTES 148192

__device__ __forceinline__ float sigm(float x) { return 1.0f / (1.0f + __expf(-x)); }
__device__ __forceinline__ unsigned short f2bf(float f) {
    unsigned u = __float_as_uint(f);
    return (unsigned short)((u + 0x7fffu + ((u >> 16) & 1u)) >> 16);
}
__device__ __forceinline__ float bf2f(unsigned s) { return __uint_as_float(s << 16); }

// ---------------------------------------------------------------------------
__global__ __launch_bounds__(512) void k_init(const float* __restrict__ values,
                                              float* __restrict__ ws) {
    int i = blockIdx.x * 512 + threadIdx.x;
    if (i >= WS_INIT_END) return;
    float v = 0.0f;
    if (i >= WS_ATTC) {
        int i0 = i - WS_ATTC;           // q*8192 + kk*256 + b*4 + j
        int q = i0 >> 13, rem = i0 & 8191;
        int kk = rem >> 8, r = rem & 255, b = r >> 2, j = r & 3;
        v = (q == 0) ? values[b * VSZ + kk * 4 + j] : 0.0f;
    } else if (i >= WS_ATTS) {
        int i0 = i - WS_ATTS;
        v = ((i0 >> 6) == 0) ? 1.0f : 0.0f;   // s_q: q0=1 others 0 (m_q all 0)
    }
    ws[i] = v;
}

// ---------------------------------------------------------------------------
// fp32 GEMM (K=256): C[m][n] = A[m][:256].B[n][:256] + bias1[n] (+bias2[n])
// ---------------------------------------------------------------------------
__global__ __launch_bounds__(256) void k_gemm_tn(
        const float* __restrict__ A, int lda,
        const float* __restrict__ B, int ldb,
        const float* __restrict__ bias1, const float* __restrict__ bias2,
        float* __restrict__ C, int ldc) {
    const int tid = threadIdx.x;
    const int m0 = blockIdx.y * 64, n0 = blockIdx.x * 64;
    const int tx = tid & 15, ty = tid >> 4;
    const int lm = tid >> 2, lk = (tid & 3) * 8;

    __shared__ float As[32][68];
    __shared__ float Bs[32][68];
    float c[4][4] = {{0.f}};

    for (int kb = 0; kb < 256; kb += 32) {
        const float* ap = A + (size_t)(m0 + lm) * lda + kb + lk;
        const float* bp = B + (size_t)(n0 + lm) * ldb + kb + lk;
        float4 a0 = *(const float4*)(ap);
        float4 a1 = *(const float4*)(ap + 4);
        float4 b0 = *(const float4*)(bp);
        float4 b1 = *(const float4*)(bp + 4);
        __syncthreads();
        As[lk + 0][lm] = a0.x; As[lk + 1][lm] = a0.y; As[lk + 2][lm] = a0.z; As[lk + 3][lm] = a0.w;
        As[lk + 4][lm] = a1.x; As[lk + 5][lm] = a1.y; As[lk + 6][lm] = a1.z; As[lk + 7][lm] = a1.w;
        Bs[lk + 0][lm] = b0.x; Bs[lk + 1][lm] = b0.y; Bs[lk + 2][lm] = b0.z; Bs[lk + 3][lm] = b0.w;
        Bs[lk + 4][lm] = b1.x; Bs[lk + 5][lm] = b1.y; Bs[lk + 6][lm] = b1.z; Bs[lk + 7][lm] = b1.w;
        __syncthreads();
#pragma unroll
        for (int kk = 0; kk < 32; ++kk) {
            const float4 a = *(const float4*)&As[kk][ty * 4];
            const float4 b = *(const float4*)&Bs[kk][tx * 4];
            c[0][0] += a.x * b.x; c[0][1] += a.x * b.y; c[0][2] += a.x * b.z; c[0][3] += a.x * b.w;
            c[1][0] += a.y * b.x; c[1][1] += a.y * b.y; c[1][2] += a.y * b.z; c[1][3] += a.y * b.w;
            c[2][0] += a.z * b.x; c[2][1] += a.z * b.y; c[2][2] += a.z * b.z; c[2][3] += a.z * b.w;
            c[3][0] += a.w * b.x; c[3][1] += a.w * b.y; c[3][2] += a.w * b.z; c[3][3] += a.w * b.w;
        }
    }
    const int n = n0 + tx * 4;
    float4 bb = *(const float4*)&bias1[n];
    if (bias2) {
        float4 b2 = *(const float4*)&bias2[n];
        bb.x += b2.x; bb.y += b2.y; bb.z += b2.z; bb.w += b2.w;
    }
#pragma unroll
    for (int i = 0; i < 4; ++i) {
        float4 r;
        r.x = c[i][0] + bb.x; r.y = c[i][1] + bb.y; r.z = c[i][2] + bb.z; r.w = c[i][3] + bb.w;
        *(float4*)&C[(size_t)(m0 + ty * 4 + i) * ldc + n] = r;
    }
}

// ---------------------------------------------------------------------------
// grid barrier: monotonic counters, relaxed spin, single release/acquire fence
// ---------------------------------------------------------------------------
__device__ __forceinline__ void gridbar(unsigned* bar, unsigned bk, int blk) {
    __syncthreads();
    if (threadIdx.x == 0) {
        __builtin_amdgcn_fence(__ATOMIC_RELEASE, "agent");
        unsigned* cnt = bar + 32 + ((blk & 15) << 5);
        unsigned a = __hip_atomic_fetch_add(cnt, 1u, __ATOMIC_RELAXED, __HIP_MEMORY_SCOPE_AGENT);
        if (a == bk * 16u - 1u) {
            unsigned ma = __hip_atomic_fetch_add(bar + 16, 1u, __ATOMIC_RELAXED, __HIP_MEMORY_SCOPE_AGENT);
            if (ma == bk * 16u - 1u)
                __hip_atomic_store(bar, bk, __ATOMIC_RELAXED, __HIP_MEMORY_SCOPE_AGENT);
        }
        while (__hip_atomic_load(bar, __ATOMIC_RELAXED, __HIP_MEMORY_SCOPE_AGENT) < bk)
            __builtin_amdgcn_s_sleep(2);
        __builtin_amdgcn_fence(__ATOMIC_ACQUIRE, "agent");
    }
    __syncthreads();
}

// merge quarters and write one h2ctx ctx row (threads tid<128)
__device__ __forceinline__ void write_ctx_row(const float* wm, const float* wsv,
                                              const float* wcv, float* h2ctx,
                                              int b, int l, int tid) {
    if (tid < 128) {
        float m0 = wm[b], m1 = wm[64 + b], m2 = wm[128 + b], m3 = wm[192 + b];
        float M = fmaxf(fmaxf(m0, m1), fmaxf(m2, m3));
        float w0 = __expf(m0 - M), w1 = __expf(m1 - M);
        float w2 = __expf(m2 - M), w3 = __expf(m3 - M);
        float S = w0 * wsv[b] + w1 * wsv[64 + b] + w2 * wsv[128 + b] + w3 * wsv[192 + b];
        float inv = 1.0f / S;
        int off = (tid >> 2) * 256 + b * 4 + (tid & 3);
        float c = w0 * wcv[off] + w1 * wcv[8192 + off] + w2 * wcv[16384 + off] + w3 * wcv[24576 + off];
        h2ctx[((size_t)b * LL + l) * 256 + 128 + tid] = c * inv;
    }
}

// ---------------------------------------------------------------------------
// Persistent kernel: 250 steps, 256 blocks x 512 threads, 3 barriers/step.
// Key(fp32)+values(bf16) slices pinned in LDS for the whole kernel.
// ---------------------------------------------------------------------------
__global__ __launch_bounds__(512) void k_loop(
        const float* __restrict__ key, const float* __restrict__ values,
        const int* __restrict__ speech_len, const int* __restrict__ text,
        const float* __restrict__ EmbW,
        const float* __restrict__ w_ih1, const float* __restrict__ w_hh1,
        const float* __restrict__ w_ih2, const float* __restrict__ b_ih2,
        const float* __restrict__ w_hh2, const float* __restrict__ b_hh2,
        float* __restrict__ ws) {
    extern __shared__ char smem[];
    const int blk = blockIdx.x;
    const int tid = threadIdx.x;

    unsigned* bar = (unsigned*)ws;
    float* xTb[2]  = { ws + WS_XT0, ws + WS_XT1 };
    float* h2Tb[2] = { ws + WS_H2T0, ws + WS_H2T1 };
    float* h2rm    = ws + WS_H2RM;
    float* wm      = ws + WS_ATTM;
    float* wsv     = ws + WS_ATTS;
    float* wcv     = ws + WS_ATTC;
    float* h2ctx   = ws + WS_H2CTX;

    float*    sW1p  = (float*)(smem + OFF_W1);
    float*    sW2p  = (float*)(smem + OFF_W2);
    float*    redp  = (float*)(smem + OFF_RED);
    float4*   skey4 = (float4*)(smem + OFF_KEY);
    unsigned* svalw = (unsigned*)(smem + OFF_VAL);
    float4*   h2s4  = (float4*)(smem + OFF_H2S);
    float*    scp   = (float*)(smem + OFF_SC);
    float*    smf   = (float*)(smem + OFF_SM);

    const int h0 = blk * 2;
    const int cb = blk >> 2, ctq = blk & 3;       // attention role (b, t-quarter)

    // ---- prologue: LDS-resident weights + key/values slices ----
#pragma unroll
    for (int j = 0; j < 8; ++j) {
        int hl = j >> 2, g = j & 3;
        int row = g * 512 + h0 + hl;
        for (int k = tid; k < 640; k += 512)
            sW1p[j * 640 + k] = (k < 128) ? w_ih1[row * 384 + 256 + k]
                                          : w_hh1[row * 512 + k - 128];
    }
    if (blk < 128) {
#pragma unroll
        for (int g = 0; g < 4; ++g) {
            int row = g * 128 + blk;
            for (int k = tid; k < 640; k += 512)
                sW2p[g * 640 + k] = (k < 512) ? w_ih2[row * 512 + k]
                                              : w_hh2[row * 128 + k - 512];
        }
        if (tid < 4) smf[4 + tid] = b_ih2[tid * 128 + blk] + b_hh2[tid * 128 + blk];
    }
    for (int i = tid; i < 4000; i += 512) {       // 125 t x 32 f4
        int t = i >> 5, kq = i & 31;
        size_t gro = (((size_t)(ctq * 125 + t)) * BB + cb) * 32;
        skey4[t * 34 + kq] = ((const float4*)key)[gro + kq];
        float4 vv = ((const float4*)values)[gro + kq];
        svalw[t * 64 + kq * 2]     = (unsigned)f2bf(vv.x) | ((unsigned)f2bf(vv.y) << 16);
        svalw[t * 64 + kq * 2 + 1] = (unsigned)f2bf(vv.z) | ((unsigned)f2bf(vv.w) << 16);
    }
    const int len = speech_len[cb];
    __syncthreads();

    float c1a = 0.f, c1b = 0.f, c2 = 0.f;
    unsigned bk = 0;

    for (int l = 0; l < LL; ++l) {
        const float* xcur  = xTb[l & 1];
        float*       xnext = xTb[(l & 1) ^ 1];
        const float* h2cur = h2Tb[l & 1];
        float*       h2nw  = h2Tb[(l & 1) ^ 1];

        // ================ phase A: LSTM1 (+ctx merge on the fly) ================
        {
            const int b = tid & 63;
            const int ks = tid >> 6;              // 0..7, 20 kk each
            float acc[8] = {0.f, 0.f, 0.f, 0.f, 0.f, 0.f, 0.f, 0.f};
            if (ks == 7) {
                const int tok = (l == 0) ? 0 : text[b * LL + l - 1];
                const float* er = EmbW + (size_t)tok * 2048;
#pragma unroll
                for (int j = 0; j < 8; ++j) acc[j] = er[(j & 3) * 512 + h0 + (j >> 2)];
            }
            float w0 = 0.f, w1 = 0.f, w2 = 0.f, w3 = 0.f;
            if (ks < 2) {
                float m0 = wm[b], m1 = wm[64 + b], m2 = wm[128 + b], m3 = wm[192 + b];
                float M = fmaxf(fmaxf(m0, m1), fmaxf(m2, m3));
                w0 = __expf(m0 - M); w1 = __expf(m1 - M);
                w2 = __expf(m2 - M); w3 = __expf(m3 - M);
                float S = w0 * wsv[b] + w1 * wsv[64 + b] + w2 * wsv[128 + b] + w3 * wsv[192 + b];
                float inv = 1.0f / S;
                w0 *= inv; w1 *= inv; w2 *= inv; w3 *= inv;
            }
            const float4* xc4 = (const float4*)xcur + b;
            const float4* wc4 = (const float4*)wcv + b;
            const int kk0 = ks * 20;
#pragma unroll 4
            for (int kk = kk0; kk < kk0 + 20; ++kk) {
                float4 xv;
                if (kk < 32) {
                    float4 q0 = wc4[kk * 64], q1 = wc4[2048 + kk * 64];
                    float4 q2 = wc4[4096 + kk * 64], q3 = wc4[6144 + kk * 64];
                    xv.x = w0 * q0.x + w1 * q1.x + w2 * q2.x + w3 * q3.x;
                    xv.y = w0 * q0.y + w1 * q1.y + w2 * q2.y + w3 * q3.y;
                    xv.z = w0 * q0.z + w1 * q1.z + w2 * q2.z + w3 * q3.z;
                    xv.w = w0 * q0.w + w1 * q1.w + w2 * q2.w + w3 * q3.w;
                } else {
                    xv = xc4[kk * 64];
                }
#pragma unroll
                for (int j = 0; j < 8; ++j) {
                    float4 w = *(const float4*)&sW1p[j * 640 + kk * 4];
                    acc[j] += w.x * xv.x + w.y * xv.y + w.z * xv.z + w.w * xv.w;
                }
            }
            if (ks) {
#pragma unroll
                for (int j = 0; j < 8; ++j) redp[(ks - 1) * 512 + j * 64 + b] = acc[j];
            }
            __syncthreads();
            if (ks == 0) {
#pragma unroll
                for (int j = 0; j < 8; ++j) {
                    float s = acc[j];
#pragma unroll
                    for (int p = 0; p < 7; ++p) s += redp[p * 512 + j * 64 + b];
                    acc[j] = s;
                }
#pragma unroll
                for (int hl = 0; hl < 2; ++hl) {
                    float iv = sigm(acc[hl * 4 + 0]), fv = sigm(acc[hl * 4 + 1]);
                    float gv = tanhf(acc[hl * 4 + 2]), ov = sigm(acc[hl * 4 + 3]);
                    float cr = hl ? c1b : c1a;
                    cr = fv * cr + iv * gv;
                    if (hl) c1b = cr; else c1a = cr;
                    float h1v = ov * tanhf(cr);
                    int k = 128 + h0 + hl;
                    xnext[(k >> 2) * 256 + b * 4 + (k & 3)] = h1v;
                }
            }
        }
        ++bk; gridbar(bar, bk, blk);

        // ================ phase B: LSTM2 | ctx-row writers ================
        if (blk < 128) {
            const int b = tid & 63, ks = tid >> 6;
            float a0, a1, a2, a3;
            if (ks == 0) { a0 = smf[4]; a1 = smf[5]; a2 = smf[6]; a3 = smf[7]; }
            else { a0 = a1 = a2 = a3 = 0.f; }
            const float4* h1p = (const float4*)xnext + 32 * 64 + b;
            const float4* h2p = (const float4*)h2cur + b;
            const int kk0 = ks * 20;
#pragma unroll 4
            for (int kkB = kk0; kkB < kk0 + 20; ++kkB) {
                float4 xv = (kkB < 128) ? h1p[kkB * 64] : h2p[(kkB - 128) * 64];
                float4 w;
                w = *(const float4*)&sW2p[kkB * 4];        a0 += w.x*xv.x + w.y*xv.y + w.z*xv.z + w.w*xv.w;
                w = *(const float4*)&sW2p[640 + kkB * 4];  a1 += w.x*xv.x + w.y*xv.y + w.z*xv.z + w.w*xv.w;
                w = *(const float4*)&sW2p[1280 + kkB * 4]; a2 += w.x*xv.x + w.y*xv.y + w.z*xv.z + w.w*xv.w;
                w = *(const float4*)&sW2p[1920 + kkB * 4]; a3 += w.x*xv.x + w.y*xv.y + w.z*xv.z + w.w*xv.w;
            }
            if (ks) {
                redp[(ks - 1) * 256 + b] = a0;
                redp[(ks - 1) * 256 + 64 + b] = a1;
                redp[(ks - 1) * 256 + 128 + b] = a2;
                redp[(ks - 1) * 256 + 192 + b] = a3;
            }
            __syncthreads();
            if (ks == 0) {
#pragma unroll
                for (int p = 0; p < 7; ++p) {
                    a0 += redp[p * 256 + b];       a1 += redp[p * 256 + 64 + b];
                    a2 += redp[p * 256 + 128 + b]; a3 += redp[p * 256 + 192 + b];
                }
                float iv = sigm(a0), fv = sigm(a1), gv = tanhf(a2), ov = sigm(a3);
                c2 = fv * c2 + iv * gv;
                float h2v = ov * tanhf(c2);
                const int r = blk;
                h2nw[(r >> 2) * 256 + b * 4 + (r & 3)] = h2v;
                h2rm[b * 128 + r] = h2v;
                h2ctx[((size_t)b * LL + l) * 256 + r] = h2v;
            }
        } else if (blk >= 192 && l > 0) {
            write_ctx_row(wm, wsv, wcv, h2ctx, blk - 192, l - 1, tid);
        }
        ++bk; gridbar(bar, bk, blk);

        // ================ phase C1: local attention on LDS slice ================
        {
            if (tid < 32) h2s4[tid * 5] = ((const float4*)(h2rm + cb * 128))[tid];
            __syncthreads();
            const int tl = tid >> 2, kq = tid & 3;
            float me = -1e30f;
            if (tl < 125) {
                float e = 0.f;
#pragma unroll
                for (int i = 0; i < 8; ++i) {
                    const int c = kq + 4 * i;
                    float4 kv = skey4[tl * 34 + c];
                    float4 hv = h2s4[c * 5];
                    e += kv.x * hv.x + kv.y * hv.y + kv.z * hv.z + kv.w * hv.w;
                }
                e += __shfl_xor(e, 1);
                e += __shfl_xor(e, 2);
                me = ((ctq * 125 + tl) < len) ? e : 0.0f;
            }
            if (kq == 0) scp[tl] = me;
            __syncthreads();
            if (tid < 64) {
                float v = fmaxf(scp[tid], scp[tid + 64]);
#pragma unroll
                for (int s = 32; s; s >>= 1) v = fmaxf(v, __shfl_xor(v, s));
                if (tid == 0) smf[0] = v;
            }
            __syncthreads();
            const float m = smf[0];
            if (kq == 0) scp[tl] = (tl < 125) ? __expf(me - m) : 0.0f;
            __syncthreads();
            if (tid < 64) {
                float v = scp[tid] + scp[tid + 64];
#pragma unroll
                for (int s = 32; s; s >>= 1) v += __shfl_xor(v, s);
                if (tid == 0) { wm[ctq * 64 + cb] = m; wsv[ctq * 64 + cb] = v; }
            }
            // partial context over this quarter (values bf16 in LDS)
            const int v2 = tid & 63, ts = tid >> 6;
            float ax = 0.f, ay = 0.f;
            const unsigned* valw = svalw + v2;
            for (int t = ts; t < 125; t += 8) {
                unsigned u = valw[t * 64];
                float p = scp[t];
                ax += p * bf2f(u & 0xffffu);
                ay += p * bf2f(u >> 16);
            }
            redp[ts * 128 + v2 * 2] = ax;
            redp[ts * 128 + v2 * 2 + 1] = ay;
            __syncthreads();
            if (tid < 128) {
                float c = 0.f;
#pragma unroll
                for (int q8 = 0; q8 < 8; ++q8) c += redp[q8 * 128 + tid];
                wcv[ctq * 8192 + (tid >> 2) * 256 + cb * 4 + (tid & 3)] = c;
            }
        }
        ++bk; gridbar(bar, bk, blk);
    }

    // final ctx row (l = 249)
    if (blk >= 192) write_ctx_row(wm, wsv, wcv, h2ctx, blk - 192, LL - 1, tid);
}

// ---------------------------------------------------------------------------
extern "C" void kernel_launch(void* const* d_in, const int* in_sizes, int n_in,
                              void* d_out, int out_size, void* d_ws, size_t ws_size,
                              hipStream_t stream) {
    const float* key        = (const float*)d_in[0];
    const float* values     = (const float*)d_in[1];
    const int*   speech_len = (const int*)d_in[2];
    const int*   text       = (const int*)d_in[3];
    const float* embedding  = (const float*)d_in[4];
    const float* w_ih1 = (const float*)d_in[5];
    const float* b_ih1 = (const float*)d_in[6];
    const float* w_hh1 = (const float*)d_in[7];
    const float* b_hh1 = (const float*)d_in[8];
    const float* w_ih2 = (const float*)d_in[9];
    const float* b_ih2 = (const float*)d_in[10];
    const float* w_hh2 = (const float*)d_in[11];
    const float* b_hh2 = (const float*)d_in[12];
    const float* w_out = (const float*)d_in[13];
    const float* b_out = (const float*)d_in[14];
    float* out = (float*)d_out;

    float* ws    = (float*)d_ws;
    float* h2ctx = ws + WS_H2CTX;
    float* EmbW  = out;  // 4096x2048 scratch at head of out; overwritten by final GEMM

    (void)hipFuncSetAttribute((const void*)k_loop,
                              hipFuncAttributeMaxDynamicSharedMemorySize, LDS_BYTES);

    k_init<<<275, 512, 0, stream>>>(values, ws);
    k_gemm_tn<<<dim3(32, 64), 256, 0, stream>>>(embedding, 256, w_ih1, 384,
                                                b_ih1, b_hh1, EmbW, 2048);
    k_loop<<<NBLK, 512, LDS_BYTES, stream>>>(key, values, speech_len, text, EmbW,
                                             w_ih1, w_hh1, w_ih2, b_ih2, w_hh2, b_hh2, ws);
    k_gemm_tn<<<dim3(64, 250), 256, 0, stream>>>(h2ctx, 256, w_out, 256,
                                                 b_out, nullptr, out, 4096);
}

// Round 5
// 10490.528 us; speedup vs baseline: 5.1449x; 1.1561x over previous
//
#include <hip/hip_runtime.h>
#include <hip/hip_fp16.h>

#define TT 500
#define BB 64
#define LL 250
#define NBLK 256

// ---- ws layout (float/u32 index units) ----
#define WS_BAR    0                 // 1024
#define WS_XG     1024              // [2][64 b][320 kp] u32 (ctx 64 pairs | h1 256 pairs)
#define WS_H2G    41984             // [2][64 b][64 kp] u32
#define WS_WC     50176             // [3 ts][64 b][64 vp] u32 fp16-pairs
#define WS_WMS    62464             // [3][64][2] f32 (m,s)
#define WS_H2CTX  62848             // [64*250][256] f32
// end = 62848 + 4096000

// ---- out scratch (float index units) ----
#define OUT_EMBW  0                 // 4096*2048 f32
#define OUT_EG    8388608           // 250*2048*64 u16 -> 16777216 floats
#define OUT_WP1   25165824          // 2048*320 u32
#define OUT_WP2   25821184          // 512*320 u32
#define OUT_KEYG  25985024          // 64*500*64 u32
#define OUT_VALG  28033024          // 64*128*250 u32  (end 30081024 < 65536000)

// ---- k_loop LDS (bytes) ----
#define L_W1   0                    // [16][320] u32 = 20480
#define L_UNI  20480                // union region, 41216 (xL [32][322] u32)
#define L_XBL  20480                //   B: [8][322] u32 = 10304
#define L_RED2 30784                //   B: [64][8] f32 = 2048
#define L_ERED 20480                //   C: [2][168] f32 = 1344
#define L_SPH  22496                //   C: [84] u32
#define L_H2L  22832                //   C: [64] u32
#define L_SMX  23088                //   C: [8] f32
#define L_CRED 23120                //   C: [4][128] f32 = 2048
#define L_REDA 61696                // [16][32] f32 = 2048
#define L_ROLE 63744
// B: w2L [64][324] u32 = 82944 -> 146688 ; b2L [64] f32 -> 146944
// C: keyL [168][70] u32 = 47040 -> 110784 ; valL [128][85] u32 = 43520 -> 154304
#define LDS_BYTES 154304

__device__ __forceinline__ float sigm(float x) { return 1.0f / (1.0f + __expf(-x)); }

__device__ __forceinline__ unsigned pk(float a, float b) {
    __half2 h;
    h.x = __float2half_rn(a); h.y = __float2half_rn(b);
    unsigned u; __builtin_memcpy(&u, &h, 4); return u;
}
__device__ __forceinline__ float2 upk(unsigned u) {
    __half2 h; __builtin_memcpy(&h, &u, 4);
    return make_float2(__half2float(h.x), __half2float(h.y));
}

#ifndef __has_builtin
#define __has_builtin(x) 0
#endif
#if __has_builtin(__builtin_amdgcn_fdot2)
typedef _Float16 h2vec __attribute__((ext_vector_type(2)));
__device__ __forceinline__ float dot2(unsigned a, unsigned b, float c) {
    h2vec ha, hb;
    __builtin_memcpy(&ha, &a, 4); __builtin_memcpy(&hb, &b, 4);
    return __builtin_amdgcn_fdot2(ha, hb, c, false);
}
#else
__device__ __forceinline__ float dot2(unsigned a, unsigned b, float c) {
    float2 fa = upk(a), fb = upk(b);
    return c + fa.x * fb.x + fa.y * fb.y;
}
#endif

// ---------------------------------------------------------------------------
__global__ __launch_bounds__(512) void k_init(const float* __restrict__ values,
                                              float* __restrict__ ws) {
    int i = blockIdx.x * 512 + threadIdx.x;
    if (i >= 62848) return;
    unsigned* wsu = (unsigned*)ws;
    if (i >= WS_WC && i < WS_WC + 4096) {          // wc[0][b][vp] = values[t=0]
        int r = i - WS_WC; int b = r >> 6, vp = r & 63;
        wsu[i] = pk(values[b * 128 + 2 * vp], values[b * 128 + 2 * vp + 1]);
    } else if (i >= WS_WMS) {
        int r = i - WS_WMS;                        // ts0: s=1, everything else 0
        ws[i] = (r < 128 && (r & 1)) ? 1.0f : 0.0f;
    } else {
        ws[i] = 0.0f;
    }
}

// ---------------------------------------------------------------------------
// pack weights/key/values to fp16 pairs
// ---------------------------------------------------------------------------
#define PK_W1 655360
#define PK_W2 819200
#define PK_KEY 2867200
#define PK_TOT 4915200
__global__ __launch_bounds__(512) void k_pack(
        const float* __restrict__ key, const float* __restrict__ values,
        const float* __restrict__ w_ih1, const float* __restrict__ w_hh1,
        const float* __restrict__ w_ih2, const float* __restrict__ w_hh2,
        unsigned* __restrict__ wp1, unsigned* __restrict__ wp2,
        unsigned* __restrict__ keyg, unsigned* __restrict__ valg) {
    int idx = blockIdx.x * 512 + threadIdx.x;
    if (idx >= PK_TOT) return;
    if (idx < PK_W1) {
        int j = idx / 320, kp = idx % 320, k0 = 2 * kp;
        float a, b;
        if (k0 < 128) { a = w_ih1[j * 384 + 256 + k0]; b = w_ih1[j * 384 + 257 + k0]; }
        else          { a = w_hh1[j * 512 + k0 - 128]; b = w_hh1[j * 512 + k0 - 127]; }
        wp1[idx] = pk(a, b);
    } else if (idx < PK_W2) {
        int i2 = idx - PK_W1;
        int j = i2 / 320, kp = i2 % 320, k0 = 2 * kp;
        float a, b;
        if (k0 < 512) { a = w_ih2[j * 512 + k0]; b = w_ih2[j * 512 + k0 + 1]; }
        else          { a = w_hh2[j * 128 + k0 - 512]; b = w_hh2[j * 128 + k0 - 511]; }
        wp2[i2] = pk(a, b);
    } else if (idx < PK_KEY) {
        int i2 = idx - PK_W2;
        int b = i2 / 32000, r = i2 % 32000, t = r >> 6, kp = r & 63;
        const float* kr = key + ((size_t)t * BB + b) * 128 + 2 * kp;
        keyg[i2] = pk(kr[0], kr[1]);
    } else {
        int i2 = idx - PK_KEY;
        int b = i2 / 32000, r = i2 % 32000, tp = r >> 7, v = r & 127;
        valg[b * 32000 + v * 250 + tp] =
            pk(values[((size_t)(2 * tp) * BB + b) * 128 + v],
               values[((size_t)(2 * tp + 1) * BB + b) * 128 + v]);
    }
}

// ---------------------------------------------------------------------------
// EG[l][j][b] fp16 = EmbW[tok(b,l)][j]
// ---------------------------------------------------------------------------
__global__ __launch_bounds__(512) void k_eg(const int* __restrict__ text,
                                            const float* __restrict__ EmbW,
                                            unsigned short* __restrict__ EG) {
    const int jc = blockIdx.x, l = blockIdx.y;
    const int tid = threadIdx.x;
    __shared__ int tokL[64];
    if (tid < 64) tokL[tid] = (l == 0) ? 0 : text[tid * LL + l - 1];
    __syncthreads();
    const int b = tid & 63, jj = tid >> 6;
    const int tok = tokL[b];
    for (int q = 0; q < 32; ++q) {
        int j = jc * 256 + jj * 32 + q;
        float v = EmbW[(size_t)tok * 2048 + j];
        __half h = __float2half_rn(v);
        unsigned short us; __builtin_memcpy(&us, &h, 2);
        EG[((size_t)l * 2048 + j) * 64 + b] = us;
    }
}

// ---------------------------------------------------------------------------
// fp32 GEMM (K=256) — EmbW precompute and final projection
// ---------------------------------------------------------------------------
__global__ __launch_bounds__(256) void k_gemm_tn(
        const float* __restrict__ A, int lda,
        const float* __restrict__ B, int ldb,
        const float* __restrict__ bias1, const float* __restrict__ bias2,
        float* __restrict__ C, int ldc) {
    const int tid = threadIdx.x;
    const int m0 = blockIdx.y * 64, n0 = blockIdx.x * 64;
    const int tx = tid & 15, ty = tid >> 4;
    const int lm = tid >> 2, lk = (tid & 3) * 8;
    __shared__ float As[32][68];
    __shared__ float Bs[32][68];
    float c[4][4] = {{0.f}};
    for (int kb = 0; kb < 256; kb += 32) {
        const float* ap = A + (size_t)(m0 + lm) * lda + kb + lk;
        const float* bp = B + (size_t)(n0 + lm) * ldb + kb + lk;
        float4 a0 = *(const float4*)(ap);
        float4 a1 = *(const float4*)(ap + 4);
        float4 b0 = *(const float4*)(bp);
        float4 b1 = *(const float4*)(bp + 4);
        __syncthreads();
        As[lk + 0][lm] = a0.x; As[lk + 1][lm] = a0.y; As[lk + 2][lm] = a0.z; As[lk + 3][lm] = a0.w;
        As[lk + 4][lm] = a1.x; As[lk + 5][lm] = a1.y; As[lk + 6][lm] = a1.z; As[lk + 7][lm] = a1.w;
        Bs[lk + 0][lm] = b0.x; Bs[lk + 1][lm] = b0.y; Bs[lk + 2][lm] = b0.z; Bs[lk + 3][lm] = b0.w;
        Bs[lk + 4][lm] = b1.x; Bs[lk + 5][lm] = b1.y; Bs[lk + 6][lm] = b1.z; Bs[lk + 7][lm] = b1.w;
        __syncthreads();
#pragma unroll
        for (int kk = 0; kk < 32; ++kk) {
            const float4 a = *(const float4*)&As[kk][ty * 4];
            const float4 b = *(const float4*)&Bs[kk][tx * 4];
            c[0][0] += a.x * b.x; c[0][1] += a.x * b.y; c[0][2] += a.x * b.z; c[0][3] += a.x * b.w;
            c[1][0] += a.y * b.x; c[1][1] += a.y * b.y; c[1][2] += a.y * b.z; c[1][3] += a.y * b.w;
            c[2][0] += a.z * b.x; c[2][1] += a.z * b.y; c[2][2] += a.z * b.z; c[2][3] += a.z * b.w;
            c[3][0] += a.w * b.x; c[3][1] += a.w * b.y; c[3][2] += a.w * b.z; c[3][3] += a.w * b.w;
        }
    }
    const int n = n0 + tx * 4;
    float4 bb = *(const float4*)&bias1[n];
    if (bias2) {
        float4 b2 = *(const float4*)&bias2[n];
        bb.x += b2.x; bb.y += b2.y; bb.z += b2.z; bb.w += b2.w;
    }
#pragma unroll
    for (int i = 0; i < 4; ++i) {
        float4 r;
        r.x = c[i][0] + bb.x; r.y = c[i][1] + bb.y; r.z = c[i][2] + bb.z; r.w = c[i][3] + bb.w;
        *(float4*)&C[(size_t)(m0 + ty * 4 + i) * ldc + n] = r;
    }
}

// ---------------------------------------------------------------------------
// grid barrier (R4-proven): monotonic counters, relaxed spin, single fences
// ---------------------------------------------------------------------------
__device__ __forceinline__ void gridbar(unsigned* bar, unsigned bk, int blk) {
    __syncthreads();
    if (threadIdx.x == 0) {
        __builtin_amdgcn_fence(__ATOMIC_RELEASE, "agent");
        unsigned* cnt = bar + 32 + ((blk & 15) << 5);
        unsigned a = __hip_atomic_fetch_add(cnt, 1u, __ATOMIC_RELAXED, __HIP_MEMORY_SCOPE_AGENT);
        if (a == bk * 16u - 1u) {
            unsigned ma = __hip_atomic_fetch_add(bar + 16, 1u, __ATOMIC_RELAXED, __HIP_MEMORY_SCOPE_AGENT);
            if (ma == bk * 16u - 1u)
                __hip_atomic_store(bar, bk, __ATOMIC_RELAXED, __HIP_MEMORY_SCOPE_AGENT);
        }
        while (__hip_atomic_load(bar, __ATOMIC_RELAXED, __HIP_MEMORY_SCOPE_AGENT) < bk)
            __builtin_amdgcn_s_sleep(2);
        __builtin_amdgcn_fence(__ATOMIC_ACQUIRE, "agent");
    }
    __syncthreads();
}

// merge 3 attention slices (exact): ctx = sum_q w_q*c_q / sum_q w_q*s_q
__device__ __forceinline__ void ctx_merge_write(const unsigned* __restrict__ wcu,
                                                const float* __restrict__ wms,
                                                unsigned* xLdst, float* h2dst,
                                                int b, int q) {
    float m0 = wms[(0 * 64 + b) * 2], s0 = wms[(0 * 64 + b) * 2 + 1];
    float m1 = wms[(1 * 64 + b) * 2], s1 = wms[(1 * 64 + b) * 2 + 1];
    float m2 = wms[(2 * 64 + b) * 2], s2 = wms[(2 * 64 + b) * 2 + 1];
    float M = fmaxf(m0, fmaxf(m1, m2));
    float w0 = __expf(m0 - M), w1 = __expf(m1 - M), w2 = __expf(m2 - M);
    float inv = 1.0f / (w0 * s0 + w1 * s1 + w2 * s2);
    w0 *= inv; w1 *= inv; w2 *= inv;
    uint4 p0 = *(const uint4*)&wcu[(0 * 64 + b) * 64 + q * 4];
    uint4 p1 = *(const uint4*)&wcu[(1 * 64 + b) * 64 + q * 4];
    uint4 p2 = *(const uint4*)&wcu[(2 * 64 + b) * 64 + q * 4];
    float r[8];
#define MRG(comp, o) { float2 f0 = upk(p0.comp), f1 = upk(p1.comp), f2 = upk(p2.comp); \
        r[o] = w0 * f0.x + w1 * f1.x + w2 * f2.x; \
        r[o + 1] = w0 * f0.y + w1 * f1.y + w2 * f2.y; }
    MRG(x, 0) MRG(y, 2) MRG(z, 4) MRG(w, 6)
#undef MRG
    if (xLdst) {
        xLdst[0] = pk(r[0], r[1]); xLdst[1] = pk(r[2], r[3]);
        xLdst[2] = pk(r[4], r[5]); xLdst[3] = pk(r[6], r[7]);
    }
    if (h2dst) {
        *(float4*)&h2dst[0] = make_float4(r[0], r[1], r[2], r[3]);
        *(float4*)&h2dst[4] = make_float4(r[4], r[5], r[6], r[7]);
    }
}

// ---------------------------------------------------------------------------
// Persistent kernel: 250 steps, 256 blocks x 512 threads, 3 barriers/step.
// A (all): LSTM1 tile 4h x 32b.  B (blk>=192): LSTM2 tile 16r x 8b.
// C (blk<192): attention slice (b, ts) with key/val fp16 LDS-resident.
// ---------------------------------------------------------------------------
__global__ __launch_bounds__(512) void k_loop(
        const int* __restrict__ speech_len,
        const unsigned short* __restrict__ EG,
        const unsigned* __restrict__ wp1, const unsigned* __restrict__ wp2,
        const unsigned* __restrict__ keyg, const unsigned* __restrict__ valg,
        const float* __restrict__ b_ih2, const float* __restrict__ b_hh2,
        float* __restrict__ ws) {
    extern __shared__ char smem[];
    const int blk = blockIdx.x;
    const int tid = threadIdx.x;

    unsigned* bar = (unsigned*)ws;
    unsigned* wsu = (unsigned*)ws;
    unsigned* xgb[2]  = { wsu + WS_XG, wsu + WS_XG + 20480 };
    unsigned* h2gb[2] = { wsu + WS_H2G, wsu + WS_H2G + 4096 };
    unsigned* wcu = wsu + WS_WC;
    float* wms = ws + WS_WMS;
    float* h2ctx = ws + WS_H2CTX;

    unsigned* w1L  = (unsigned*)(smem + L_W1);
    unsigned* xL   = (unsigned*)(smem + L_UNI);
    float*    redA = (float*)(smem + L_REDA);
    // B role
    unsigned* xBL  = (unsigned*)(smem + L_XBL);
    float*    red2 = (float*)(smem + L_RED2);
    unsigned* w2L  = (unsigned*)(smem + L_ROLE);
    float*    b2L  = (float*)(smem + L_ROLE + 82944);
    // C role
    float*    ered = (float*)(smem + L_ERED);
    unsigned* sph  = (unsigned*)(smem + L_SPH);
    unsigned* h2L  = (unsigned*)(smem + L_H2L);
    float*    smx  = (float*)(smem + L_SMX);
    float*    cred = (float*)(smem + L_CRED);
    unsigned* keyL = (unsigned*)(smem + L_ROLE);
    unsigned* valL = (unsigned*)(smem + L_ROLE + 47040);

    const int jt = blk >> 1, bt = blk & 1;          // A tile
    const int isB = (blk >= 192);
    const int blkB = blk - 192;
    const int r0 = (blkB >> 3) * 16, bb0 = (blkB & 7) * 8;   // B tile
    const int ts = blk / 64, cb = blk & 63;          // C tile (blk<192)
    const int t0 = ts * 168;
    const int TN = (ts < 2) ? 168 : 164;
    const int TPN = (ts < 2) ? 84 : 82;
    const int tp0 = ts * 84;

    // ---- prologue: LDS-resident weights / key / values ----
    for (int row = 0; row < 16; ++row) {
        int jg = (row >> 2) * 512 + jt * 4 + (row & 3);
        for (int k = tid; k < 320; k += 512) w1L[row * 320 + k] = wp1[jg * 320 + k];
    }
    if (isB) {
        for (int rl = 0; rl < 64; ++rl) {
            int j2 = (rl >> 4) * 128 + r0 + (rl & 15);
            for (int k = tid; k < 320; k += 512) w2L[rl * 324 + k] = wp2[j2 * 320 + k];
        }
        for (int i = tid; i < 64; i += 512) {
            int j2 = (i >> 4) * 128 + r0 + (i & 15);
            b2L[i] = b_ih2[j2] + b_hh2[j2];
        }
    } else {
        for (int i = tid; i < TN * 64; i += 512) {
            int t = i >> 6, kp = i & 63;
            keyL[t * 70 + kp] = keyg[(size_t)cb * 32000 + (size_t)(t0 + t) * 64 + kp];
        }
        for (int i = tid; i < 128 * 84; i += 512) {
            int v = i / 84, tp = i % 84;
            valL[v * 85 + tp] = (tp < TPN)
                ? valg[(size_t)cb * 32000 + v * 250 + tp0 + tp] : 0u;
        }
    }
    int len = 0;
    if (!isB) len = speech_len[cb];
    __syncthreads();

    float c1 = 0.f, c2 = 0.f;
    unsigned bk = 0;

    for (int l = 0; l < LL; ++l) {
        const int cur = l & 1, nxt = cur ^ 1;
        unsigned* xg_cur = xgb[cur];
        unsigned* xg_nxt = xgb[nxt];
        unsigned* h2_cur = h2gb[cur];
        unsigned* h2_nxt = h2gb[nxt];

        // ================= phase A: LSTM1 =================
        {
            // stage h1-region of x (fp16 pairs) into LDS
            for (int i = tid; i < 2048; i += 512) {
                int bl = i >> 6, q = i & 63;
                uint4 d = *(const uint4*)&xg_cur[(bt * 32 + bl) * 320 + 64 + q * 4];
                *(uint2*)&xL[bl * 322 + 64 + q * 4] = make_uint2(d.x, d.y);
                *(uint2*)&xL[bl * 322 + 66 + q * 4] = make_uint2(d.z, d.w);
            }
            // ctx merge (1 job per thread)
            {
                int bl = tid >> 4, q = tid & 15, b = bt * 32 + bl;
                unsigned* dst = &xL[bl * 322 + q * 4];
                float* hdst = (jt == 0 && l > 0)
                    ? &h2ctx[((size_t)b * LL + (l - 1)) * 256 + 128 + q * 8] : nullptr;
                ctx_merge_write(wcu, wms, dst, hdst, b, q);
            }
            __syncthreads();

            const int j = tid >> 5, bl = tid & 31;
            const int b = bt * 32 + bl;
            const int g = j >> 2, hh = j & 3;
            const int jrow = g * 512 + jt * 4 + hh;
            const __half* EGh = (const __half*)EG;
            float acc = __half2float(EGh[((size_t)l * 2048 + jrow) * 64 + b]);
            const unsigned* wr = &w1L[j * 320];
            const unsigned* xr = &xL[bl * 322];
#pragma unroll 8
            for (int kp = 0; kp < 320; kp += 4) {
                uint4 wv = *(const uint4*)&wr[kp];
                uint2 x0 = *(const uint2*)&xr[kp];
                uint2 x1 = *(const uint2*)&xr[kp + 2];
                acc = dot2(wv.x, x0.x, acc); acc = dot2(wv.y, x0.y, acc);
                acc = dot2(wv.z, x1.x, acc); acc = dot2(wv.w, x1.y, acc);
            }
            redA[j * 32 + bl] = acc;
            __syncthreads();
            if (tid < 128) {
                int hh2 = tid >> 5, bl2 = tid & 31, b2 = bt * 32 + bl2;
                float g0 = redA[(0 * 4 + hh2) * 32 + bl2];
                float g1 = redA[(1 * 4 + hh2) * 32 + bl2];
                float g2 = redA[(2 * 4 + hh2) * 32 + bl2];
                float g3 = redA[(3 * 4 + hh2) * 32 + bl2];
                float iv = sigm(g0), fv = sigm(g1), gv = tanhf(g2), ov = sigm(g3);
                c1 = fv * c1 + iv * gv;
                float h1v = ov * tanhf(c1);
                float hp = __shfl_xor(h1v, 32);
                if (!(hh2 & 1))
                    xg_nxt[b2 * 320 + 64 + jt * 2 + (hh2 >> 1)] = pk(h1v, hp);
            }
        }
        ++bk; gridbar(bar, bk, blk);

        // ================= phase B: LSTM2 (blk>=192) =================
        if (isB) {
            {
                int bli = tid >> 6, q = tid & 63;
                uint4 d = *(const uint4*)&xg_nxt[(bb0 + bli) * 320 + 64 + q * 4];
                *(uint2*)&xBL[bli * 322 + q * 4] = make_uint2(d.x, d.y);
                *(uint2*)&xBL[bli * 322 + 2 + q * 4] = make_uint2(d.z, d.w);
            }
            if (tid < 128) {
                int bli = tid >> 4, q = tid & 15;
                uint4 d = *(const uint4*)&h2_cur[(bb0 + bli) * 64 + q * 4];
                *(uint2*)&xBL[bli * 322 + 256 + q * 4] = make_uint2(d.x, d.y);
                *(uint2*)&xBL[bli * 322 + 258 + q * 4] = make_uint2(d.z, d.w);
            }
            __syncthreads();
            const int row = tid >> 3, bli = tid & 7;
            float acc = b2L[row];
            const unsigned* wr = &w2L[row * 324];
            const unsigned* xr = &xBL[bli * 322];
#pragma unroll 8
            for (int kp = 0; kp < 320; kp += 4) {
                uint4 wv = *(const uint4*)&wr[kp];
                uint2 x0 = *(const uint2*)&xr[kp];
                uint2 x1 = *(const uint2*)&xr[kp + 2];
                acc = dot2(wv.x, x0.x, acc); acc = dot2(wv.y, x0.y, acc);
                acc = dot2(wv.z, x1.x, acc); acc = dot2(wv.w, x1.y, acc);
            }
            red2[row * 8 + bli] = acc;
            __syncthreads();
            if (tid < 128) {
                int rr = tid >> 3, bli2 = tid & 7, b = bb0 + bli2;
                float g0 = red2[(0 * 16 + rr) * 8 + bli2];
                float g1 = red2[(1 * 16 + rr) * 8 + bli2];
                float g2 = red2[(2 * 16 + rr) * 8 + bli2];
                float g3 = red2[(3 * 16 + rr) * 8 + bli2];
                float iv = sigm(g0), fv = sigm(g1), gv = tanhf(g2), ov = sigm(g3);
                c2 = fv * c2 + iv * gv;
                float h2v = ov * tanhf(c2);
                h2ctx[((size_t)b * LL + l) * 256 + r0 + rr] = h2v;
                float hp = __shfl_xor(h2v, 8);
                if (!(rr & 1))
                    h2_nxt[b * 64 + ((r0 + rr) >> 1)] = pk(h2v, hp);
            }
        }
        ++bk; gridbar(bar, bk, blk);

        // ================= phase C: attention slice (blk<192) =================
        if (!isB) {
            if (tid < 64) h2L[tid] = h2_nxt[cb * 64 + tid];
            __syncthreads();
            const int tl = tid >> 1, ph = tid & 1;
            float e = 0.f;
            if (tl < TN) {
                const unsigned* kr = &keyL[tl * 70 + ph * 32];
                const int kb = ph * 32;
#pragma unroll 8
                for (int i = 0; i < 32; i += 2) {
                    uint2 kv = *(const uint2*)&kr[i];
                    e = dot2(kv.x, h2L[kb + i], e);
                    e = dot2(kv.y, h2L[kb + i + 1], e);
                }
            }
            if (tl < 168) ered[ph * 168 + tl] = e;
            __syncthreads();
            float me = -1e30f;
            if (tid < TN) {
                float et = ered[tid] + ered[168 + tid];
                me = (t0 + tid < len) ? et : 0.0f;
            }
            float mv = me;
#pragma unroll
            for (int s = 32; s; s >>= 1) mv = fmaxf(mv, __shfl_xor(mv, s));
            if ((tid & 63) == 0 && tid < 192) smx[tid >> 6] = mv;
            __syncthreads();
            const float m = fmaxf(smx[0], fmaxf(smx[1], smx[2]));
            float p = 0.f;
            if (tid < TN) p = __expf(me - m);
            float sv = p;
#pragma unroll
            for (int s = 32; s; s >>= 1) sv += __shfl_xor(sv, s);
            if ((tid & 63) == 0 && tid < 192) smx[4 + (tid >> 6)] = sv;
            if (tid < 168) {
                float pn = __shfl_xor(p, 1);
                if (!(tid & 1)) sph[tid >> 1] = pk(p, pn);
            }
            __syncthreads();
            const float sq = smx[4] + smx[5] + smx[6];
            // partial context over this slice
            const int v = tid & 127, tg = tid >> 7;
            float a = 0.f;
            const unsigned* vr = &valL[v * 85 + tg * 21];
            const unsigned* sr = &sph[tg * 21];
#pragma unroll 7
            for (int i = 0; i < 21; ++i) a = dot2(vr[i], sr[i], a);
            cred[tg * 128 + v] = a;
            __syncthreads();
            if (tid < 128) {
                float c = cred[tid] + cred[128 + tid] + cred[256 + tid] + cred[384 + tid];
                float cn = __shfl_xor(c, 1);
                if (!(tid & 1)) wcu[(ts * 64 + cb) * 64 + (tid >> 1)] = pk(c, cn);
                if (tid == 0) { wms[(ts * 64 + cb) * 2] = m; wms[(ts * 64 + cb) * 2 + 1] = sq; }
            }
        }
        ++bk; gridbar(bar, bk, blk);
    }

    // tail: ctx row for l=249
    if (jt == 0) {
        int bl = tid >> 4, q = tid & 15, b = bt * 32 + bl;
        ctx_merge_write(wcu, wms, nullptr,
                        &h2ctx[((size_t)b * LL + (LL - 1)) * 256 + 128 + q * 8], b, q);
    }
}

// ---------------------------------------------------------------------------
extern "C" void kernel_launch(void* const* d_in, const int* in_sizes, int n_in,
                              void* d_out, int out_size, void* d_ws, size_t ws_size,
                              hipStream_t stream) {
    const float* key        = (const float*)d_in[0];
    const float* values     = (const float*)d_in[1];
    const int*   speech_len = (const int*)d_in[2];
    const int*   text       = (const int*)d_in[3];
    const float* embedding  = (const float*)d_in[4];
    const float* w_ih1 = (const float*)d_in[5];
    const float* b_ih1 = (const float*)d_in[6];
    const float* w_hh1 = (const float*)d_in[7];
    const float* b_hh1 = (const float*)d_in[8];
    const float* w_ih2 = (const float*)d_in[9];
    const float* b_ih2 = (const float*)d_in[10];
    const float* w_hh2 = (const float*)d_in[11];
    const float* b_hh2 = (const float*)d_in[12];
    const float* w_out = (const float*)d_in[13];
    const float* b_out = (const float*)d_in[14];
    float* out = (float*)d_out;

    float* ws    = (float*)d_ws;
    float* h2ctx = ws + WS_H2CTX;

    float* EmbW = out + OUT_EMBW;
    unsigned short* EG = (unsigned short*)(out + OUT_EG);
    unsigned* wp1  = (unsigned*)(out + OUT_WP1);
    unsigned* wp2  = (unsigned*)(out + OUT_WP2);
    unsigned* keyg = (unsigned*)(out + OUT_KEYG);
    unsigned* valg = (unsigned*)(out + OUT_VALG);

    (void)hipFuncSetAttribute((const void*)k_loop,
                              hipFuncAttributeMaxDynamicSharedMemorySize, LDS_BYTES);

    k_init<<<123, 512, 0, stream>>>(values, ws);
    k_pack<<<(PK_TOT + 511) / 512, 512, 0, stream>>>(key, values, w_ih1, w_hh1,
                                                     w_ih2, w_hh2, wp1, wp2, keyg, valg);
    // EmbW[v][j] = embedding[v] . w_ih1[j][:256] + b_ih1[j] + b_hh1[j]
    k_gemm_tn<<<dim3(32, 64), 256, 0, stream>>>(embedding, 256, w_ih1, 384,
                                                b_ih1, b_hh1, EmbW, 2048);
    k_eg<<<dim3(8, 250), 512, 0, stream>>>(text, EmbW, EG);
    k_loop<<<NBLK, 512, LDS_BYTES, stream>>>(speech_len, EG, wp1, wp2, keyg, valg,
                                             b_ih2, b_hh2, ws);
    // out[b*250+l][v] = h2ctx[b*250+l] . w_out[v] + b_out[v]
    k_gemm_tn<<<dim3(64, 250), 256, 0, stream>>>(h2ctx, 256, w_out, 256,
                                                 b_out, nullptr, out, 4096);
}

// Round 6
// 6719.927 us; speedup vs baseline: 8.0318x; 1.5611x over previous
//
#include <hip/hip_runtime.h>
#include <hip/hip_fp16.h>

#define TT 500
#define BB 64
#define LL 250
#define NBLK 256

typedef unsigned long long ull;

// ---- ws layout (u32 index units) ----
#define WS_BAR    0                 // 1024
#define WS_XG     1024              // [2][64 b][256 u32] fp16-pairs of h1 (512 halfs)
#define WS_H2G    33792             // [2][64 b][64 u32] fp16-pairs of h2
#define WS_WC     41984             // [3 ts][64 b][64 u32] fp16-pair partial ctx
#define WS_WMS    54272             // [3][64] x (m,s) f32 pairs
#define WS_H2CTX  54656             // [64*250][256] f32
#define WS_INIT_END 54656

// ---- out scratch (float index units) ----
#define OUT_EMBW  0                 // 4096*2048 f32
#define OUT_EG    8388608           // 250*2048*64 u16 -> 16777216 floats
#define OUT_WP1   25165824          // 2048*320 u32
#define OUT_WP2   25821184          // 512*320 u32
#define OUT_KEYG  25985024          // 64*500*64 u32
#define OUT_VALG  28033024          // 64*128*250 u32  (end 30081024 < 65536000)

// ---- k_loop LDS (bytes) ----
#define L_W1   0                    // [16][320] u32 = 20480
#define L_UNI  20480                // union region (xL [32][322] u32)
#define L_XBL  20480                //   B: [8][322] u32
#define L_RED2 30784                //   B: [64][8] f32
#define L_ERED 20480                //   C: [2][168] f32
#define L_SPH  22496                //   C: [84] u32
#define L_H2L  22832                //   C: [64] u32
#define L_SMX  23088                //   C: [8] f32
#define L_CRED 23120                //   C: [4][128] f32
#define L_REDA 61696                // [16][32] f32 = 2048
#define L_ROLE 63744
// B: w2L [64][324] u32 -> +82944 ; b2L [64] f32
// C: keyL [168][70] u32 -> +47040 ; valL [128][85] u32
#define LDS_BYTES 154304

__device__ __forceinline__ float sigm(float x) { return 1.0f / (1.0f + __expf(-x)); }

__device__ __forceinline__ unsigned pk(float a, float b) {
    __half2 h;
    h.x = __float2half_rn(a); h.y = __float2half_rn(b);
    unsigned u; __builtin_memcpy(&u, &h, 4); return u;
}
__device__ __forceinline__ float2 upk(unsigned u) {
    __half2 h; __builtin_memcpy(&h, &u, 4);
    return make_float2(__half2float(h.x), __half2float(h.y));
}

// coherent (agent-scope, L2-bypassing) exchange accessors — no fences needed
__device__ __forceinline__ ull cld64(const ull* p) {
    return __hip_atomic_load(p, __ATOMIC_RELAXED, __HIP_MEMORY_SCOPE_AGENT);
}
__device__ __forceinline__ void cst64(ull* p, ull v) {
    __hip_atomic_store(p, v, __ATOMIC_RELAXED, __HIP_MEMORY_SCOPE_AGENT);
}
__device__ __forceinline__ void cst32(unsigned* p, unsigned v) {
    __hip_atomic_store(p, v, __ATOMIC_RELAXED, __HIP_MEMORY_SCOPE_AGENT);
}

#ifndef __has_builtin
#define __has_builtin(x) 0
#endif
#if __has_builtin(__builtin_amdgcn_fdot2)
typedef _Float16 h2vec __attribute__((ext_vector_type(2)));
__device__ __forceinline__ float dot2(unsigned a, unsigned b, float c) {
    h2vec ha, hb;
    __builtin_memcpy(&ha, &a, 4); __builtin_memcpy(&hb, &b, 4);
    return __builtin_amdgcn_fdot2(ha, hb, c, false);
}
#else
__device__ __forceinline__ float dot2(unsigned a, unsigned b, float c) {
    float2 fa = upk(a), fb = upk(b);
    return c + fa.x * fb.x + fa.y * fb.y;
}
#endif

// ---------------------------------------------------------------------------
__global__ __launch_bounds__(512) void k_init(const float* __restrict__ values,
                                              float* __restrict__ ws) {
    int i = blockIdx.x * 512 + threadIdx.x;
    if (i >= WS_INIT_END) return;
    unsigned* wsu = (unsigned*)ws;
    if (i >= WS_WC && i < WS_WC + 4096) {          // wc[0][b][vp] = values[t=0]
        int r = i - WS_WC; int b = r >> 6, vp = r & 63;
        wsu[i] = pk(values[b * 128 + 2 * vp], values[b * 128 + 2 * vp + 1]);
    } else if (i >= WS_WMS) {
        int r = i - WS_WMS;                        // ts0: s=1; everything else 0
        ws[i] = (r < 128 && (r & 1)) ? 1.0f : 0.0f;
    } else {
        ws[i] = 0.0f;
    }
}

// ---------------------------------------------------------------------------
// pack weights/key/values to fp16 pairs
// ---------------------------------------------------------------------------
#define PK_W1 655360
#define PK_W2 819200
#define PK_KEY 2867200
#define PK_TOT 4915200
__global__ __launch_bounds__(512) void k_pack(
        const float* __restrict__ key, const float* __restrict__ values,
        const float* __restrict__ w_ih1, const float* __restrict__ w_hh1,
        const float* __restrict__ w_ih2, const float* __restrict__ w_hh2,
        unsigned* __restrict__ wp1, unsigned* __restrict__ wp2,
        unsigned* __restrict__ keyg, unsigned* __restrict__ valg) {
    int idx = blockIdx.x * 512 + threadIdx.x;
    if (idx >= PK_TOT) return;
    if (idx < PK_W1) {
        int j = idx / 320, kp = idx % 320, k0 = 2 * kp;
        float a, b;
        if (k0 < 128) { a = w_ih1[j * 384 + 256 + k0]; b = w_ih1[j * 384 + 257 + k0]; }
        else          { a = w_hh1[j * 512 + k0 - 128]; b = w_hh1[j * 512 + k0 - 127]; }
        wp1[idx] = pk(a, b);
    } else if (idx < PK_W2) {
        int i2 = idx - PK_W1;
        int j = i2 / 320, kp = i2 % 320, k0 = 2 * kp;
        float a, b;
        if (k0 < 512) { a = w_ih2[j * 512 + k0]; b = w_ih2[j * 512 + k0 + 1]; }
        else          { a = w_hh2[j * 128 + k0 - 512]; b = w_hh2[j * 128 + k0 - 511]; }
        wp2[i2] = pk(a, b);
    } else if (idx < PK_KEY) {
        int i2 = idx - PK_W2;
        int b = i2 / 32000, r = i2 % 32000, t = r >> 6, kp = r & 63;
        const float* kr = key + ((size_t)t * BB + b) * 128 + 2 * kp;
        keyg[i2] = pk(kr[0], kr[1]);
    } else {
        int i2 = idx - PK_KEY;
        int b = i2 / 32000, r = i2 % 32000, tp = r >> 7, v = r & 127;
        valg[b * 32000 + v * 250 + tp] =
            pk(values[((size_t)(2 * tp) * BB + b) * 128 + v],
               values[((size_t)(2 * tp + 1) * BB + b) * 128 + v]);
    }
}

// ---------------------------------------------------------------------------
// EG[l][j][b] fp16 = EmbW[tok(b,l)][j]
// ---------------------------------------------------------------------------
__global__ __launch_bounds__(512) void k_eg(const int* __restrict__ text,
                                            const float* __restrict__ EmbW,
                                            unsigned short* __restrict__ EG) {
    const int jc = blockIdx.x, l = blockIdx.y;
    const int tid = threadIdx.x;
    __shared__ int tokL[64];
    if (tid < 64) tokL[tid] = (l == 0) ? 0 : text[tid * LL + l - 1];
    __syncthreads();
    const int b = tid & 63, jj = tid >> 6;
    const int tok = tokL[b];
    for (int q = 0; q < 32; ++q) {
        int j = jc * 256 + jj * 32 + q;
        float v = EmbW[(size_t)tok * 2048 + j];
        __half h = __float2half_rn(v);
        unsigned short us; __builtin_memcpy(&us, &h, 2);
        EG[((size_t)l * 2048 + j) * 64 + b] = us;
    }
}

// ---------------------------------------------------------------------------
// fp32 GEMM (K=256) — EmbW precompute and final projection
// ---------------------------------------------------------------------------
__global__ __launch_bounds__(256) void k_gemm_tn(
        const float* __restrict__ A, int lda,
        const float* __restrict__ B, int ldb,
        const float* __restrict__ bias1, const float* __restrict__ bias2,
        float* __restrict__ C, int ldc) {
    const int tid = threadIdx.x;
    const int m0 = blockIdx.y * 64, n0 = blockIdx.x * 64;
    const int tx = tid & 15, ty = tid >> 4;
    const int lm = tid >> 2, lk = (tid & 3) * 8;
    __shared__ float As[32][68];
    __shared__ float Bs[32][68];
    float c[4][4] = {{0.f}};
    for (int kb = 0; kb < 256; kb += 32) {
        const float* ap = A + (size_t)(m0 + lm) * lda + kb + lk;
        const float* bp = B + (size_t)(n0 + lm) * ldb + kb + lk;
        float4 a0 = *(const float4*)(ap);
        float4 a1 = *(const float4*)(ap + 4);
        float4 b0 = *(const float4*)(bp);
        float4 b1 = *(const float4*)(bp + 4);
        __syncthreads();
        As[lk + 0][lm] = a0.x; As[lk + 1][lm] = a0.y; As[lk + 2][lm] = a0.z; As[lk + 3][lm] = a0.w;
        As[lk + 4][lm] = a1.x; As[lk + 5][lm] = a1.y; As[lk + 6][lm] = a1.z; As[lk + 7][lm] = a1.w;
        Bs[lk + 0][lm] = b0.x; Bs[lk + 1][lm] = b0.y; Bs[lk + 2][lm] = b0.z; Bs[lk + 3][lm] = b0.w;
        Bs[lk + 4][lm] = b1.x; Bs[lk + 5][lm] = b1.y; Bs[lk + 6][lm] = b1.z; Bs[lk + 7][lm] = b1.w;
        __syncthreads();
#pragma unroll
        for (int kk = 0; kk < 32; ++kk) {
            const float4 a = *(const float4*)&As[kk][ty * 4];
            const float4 b = *(const float4*)&Bs[kk][tx * 4];
            c[0][0] += a.x * b.x; c[0][1] += a.x * b.y; c[0][2] += a.x * b.z; c[0][3] += a.x * b.w;
            c[1][0] += a.y * b.x; c[1][1] += a.y * b.y; c[1][2] += a.y * b.z; c[1][3] += a.y * b.w;
            c[2][0] += a.z * b.x; c[2][1] += a.z * b.y; c[2][2] += a.z * b.z; c[2][3] += a.z * b.w;
            c[3][0] += a.w * b.x; c[3][1] += a.w * b.y; c[3][2] += a.w * b.z; c[3][3] += a.w * b.w;
        }
    }
    const int n = n0 + tx * 4;
    float4 bb = *(const float4*)&bias1[n];
    if (bias2) {
        float4 b2 = *(const float4*)&bias2[n];
        bb.x += b2.x; bb.y += b2.y; bb.z += b2.z; bb.w += b2.w;
    }
#pragma unroll
    for (int i = 0; i < 4; ++i) {
        float4 r;
        r.x = c[i][0] + bb.x; r.y = c[i][1] + bb.y; r.z = c[i][2] + bb.z; r.w = c[i][3] + bb.w;
        *(float4*)&C[(size_t)(m0 + ty * 4 + i) * ldc + n] = r;
    }
}

// ---------------------------------------------------------------------------
// FENCE-FREE grid barrier: all exchanged data moves via sc-coherent atomics,
// so the barrier only needs arrival ordering. __syncthreads() drains each
// wave's vmcnt (stores visible at L3) before the leader arrives. No L2
// writeback/invalidate ever happens -> caches stay warm across steps.
// ---------------------------------------------------------------------------
__device__ __forceinline__ void gridbar(unsigned* bar, unsigned bk, int blk) {
    __syncthreads();
    if (threadIdx.x == 0) {
        unsigned* cnt = bar + 32 + ((blk & 15) << 5);
        unsigned a = __hip_atomic_fetch_add(cnt, 1u, __ATOMIC_RELAXED, __HIP_MEMORY_SCOPE_AGENT);
        if (a == bk * 16u - 1u) {
            unsigned ma = __hip_atomic_fetch_add(bar + 16, 1u, __ATOMIC_RELAXED, __HIP_MEMORY_SCOPE_AGENT);
            if (ma == bk * 16u - 1u)
                __hip_atomic_store(bar, bk, __ATOMIC_RELAXED, __HIP_MEMORY_SCOPE_AGENT);
        }
        while (__hip_atomic_load(bar, __ATOMIC_RELAXED, __HIP_MEMORY_SCOPE_AGENT) < bk)
            __builtin_amdgcn_s_sleep(2);
    }
    __syncthreads();
}

// merge 3 attention slices (exact): ctx = sum_q w_q*c_q / sum_q w_q*s_q
__device__ __forceinline__ void ctx_merge_write(const ull* __restrict__ wc64,
                                                const ull* __restrict__ wms64,
                                                unsigned* xLdst, float* h2dst,
                                                int b, int q) {
    float m[3], s[3];
#pragma unroll
    for (int t = 0; t < 3; ++t) {
        ull v = cld64(&wms64[t * 64 + b]);
        float2 f; __builtin_memcpy(&f, &v, 8);
        m[t] = f.x; s[t] = f.y;
    }
    float M = fmaxf(m[0], fmaxf(m[1], m[2]));
    float w0 = __expf(m[0] - M), w1 = __expf(m[1] - M), w2 = __expf(m[2] - M);
    float inv = 1.0f / (w0 * s[0] + w1 * s[1] + w2 * s[2]);
    w0 *= inv; w1 *= inv; w2 *= inv;
    unsigned p0[4], p1[4], p2[4];
    {
        ull a0 = cld64(&wc64[(0 * 64 + b) * 32 + q * 2]);
        ull a1 = cld64(&wc64[(0 * 64 + b) * 32 + q * 2 + 1]);
        __builtin_memcpy(p0, &a0, 8); __builtin_memcpy(p0 + 2, &a1, 8);
        ull b0 = cld64(&wc64[(1 * 64 + b) * 32 + q * 2]);
        ull b1 = cld64(&wc64[(1 * 64 + b) * 32 + q * 2 + 1]);
        __builtin_memcpy(p1, &b0, 8); __builtin_memcpy(p1 + 2, &b1, 8);
        ull c0 = cld64(&wc64[(2 * 64 + b) * 32 + q * 2]);
        ull c1 = cld64(&wc64[(2 * 64 + b) * 32 + q * 2 + 1]);
        __builtin_memcpy(p2, &c0, 8); __builtin_memcpy(p2 + 2, &c1, 8);
    }
    float r[8];
#pragma unroll
    for (int i = 0; i < 4; ++i) {
        float2 f0 = upk(p0[i]), f1 = upk(p1[i]), f2 = upk(p2[i]);
        r[2 * i]     = w0 * f0.x + w1 * f1.x + w2 * f2.x;
        r[2 * i + 1] = w0 * f0.y + w1 * f1.y + w2 * f2.y;
    }
    if (xLdst) {
        xLdst[0] = pk(r[0], r[1]); xLdst[1] = pk(r[2], r[3]);
        xLdst[2] = pk(r[4], r[5]); xLdst[3] = pk(r[6], r[7]);
    }
    if (h2dst) {
        *(float4*)&h2dst[0] = make_float4(r[0], r[1], r[2], r[3]);
        *(float4*)&h2dst[4] = make_float4(r[4], r[5], r[6], r[7]);
    }
}

// ---------------------------------------------------------------------------
// Persistent kernel: 250 steps, 256 blocks x 512 threads, 3 barriers/step.
// A (all): LSTM1 tile 4h x 32b.  B (blk>=192): LSTM2 tile 16r x 8b.
// C (blk<192): attention slice (b, ts) with key/val fp16 LDS-resident.
// All cross-block exchange via sc-coherent relaxed atomics; no cache fences.
// ---------------------------------------------------------------------------
__global__ __launch_bounds__(512) void k_loop(
        const int* __restrict__ speech_len,
        const unsigned short* __restrict__ EG,
        const unsigned* __restrict__ wp1, const unsigned* __restrict__ wp2,
        const unsigned* __restrict__ keyg, const unsigned* __restrict__ valg,
        const float* __restrict__ b_ih2, const float* __restrict__ b_hh2,
        float* __restrict__ ws) {
    extern __shared__ char smem[];
    const int blk = blockIdx.x;
    const int tid = threadIdx.x;

    unsigned* bar = (unsigned*)ws;
    unsigned* wsu = (unsigned*)ws;
    ull*      xg64[2]  = { (ull*)(wsu + WS_XG), (ull*)(wsu + WS_XG + 16384) };
    unsigned* xg32[2]  = { wsu + WS_XG, wsu + WS_XG + 16384 };
    ull*      h264[2]  = { (ull*)(wsu + WS_H2G), (ull*)(wsu + WS_H2G + 4096) };
    unsigned* h232[2]  = { wsu + WS_H2G, wsu + WS_H2G + 4096 };
    ull*      wc64 = (ull*)(wsu + WS_WC);
    unsigned* wc32 = wsu + WS_WC;
    ull*      wms64 = (ull*)(wsu + WS_WMS);
    float*    h2ctx = ws + WS_H2CTX;

    unsigned* w1L  = (unsigned*)(smem + L_W1);
    unsigned* xL   = (unsigned*)(smem + L_UNI);
    float*    redA = (float*)(smem + L_REDA);
    // B role
    unsigned* xBL  = (unsigned*)(smem + L_XBL);
    float*    red2 = (float*)(smem + L_RED2);
    unsigned* w2L  = (unsigned*)(smem + L_ROLE);
    float*    b2L  = (float*)(smem + L_ROLE + 82944);
    // C role
    float*    ered = (float*)(smem + L_ERED);
    unsigned* sph  = (unsigned*)(smem + L_SPH);
    unsigned* h2L  = (unsigned*)(smem + L_H2L);
    float*    smx  = (float*)(smem + L_SMX);
    float*    cred = (float*)(smem + L_CRED);
    unsigned* keyL = (unsigned*)(smem + L_ROLE);
    unsigned* valL = (unsigned*)(smem + L_ROLE + 47040);

    const int jt = blk >> 1, bt = blk & 1;          // A tile
    const int isB = (blk >= 192);
    const int blkB = blk - 192;
    const int r0 = (blkB >> 3) * 16, bb0 = (blkB & 7) * 8;   // B tile
    const int ts = blk / 64, cb = blk & 63;          // C tile (blk<192)
    const int t0 = ts * 168;
    const int TN = (ts < 2) ? 168 : 164;
    const int TPN = (ts < 2) ? 84 : 82;
    const int tp0 = ts * 84;

    // ---- prologue: LDS-resident weights / key / values ----
    for (int row = 0; row < 16; ++row) {
        int jg = (row >> 2) * 512 + jt * 4 + (row & 3);
        for (int k = tid; k < 320; k += 512) w1L[row * 320 + k] = wp1[jg * 320 + k];
    }
    if (isB) {
        for (int rl = 0; rl < 64; ++rl) {
            int j2 = (rl >> 4) * 128 + r0 + (rl & 15);
            for (int k = tid; k < 320; k += 512) w2L[rl * 324 + k] = wp2[j2 * 320 + k];
        }
        for (int i = tid; i < 64; i += 512) {
            int j2 = (i >> 4) * 128 + r0 + (i & 15);
            b2L[i] = b_ih2[j2] + b_hh2[j2];
        }
    } else {
        for (int i = tid; i < TN * 64; i += 512) {
            int t = i >> 6, kp = i & 63;
            keyL[t * 70 + kp] = keyg[(size_t)cb * 32000 + (size_t)(t0 + t) * 64 + kp];
        }
        for (int i = tid; i < 128 * 84; i += 512) {
            int v = i / 84, tp = i % 84;
            valL[v * 85 + tp] = (tp < TPN)
                ? valg[(size_t)cb * 32000 + v * 250 + tp0 + tp] : 0u;
        }
    }
    int len = 0;
    if (!isB) len = speech_len[cb];
    __syncthreads();

    float c1 = 0.f, c2 = 0.f;
    unsigned bk = 0;

    for (int l = 0; l < LL; ++l) {
        const int cur = l & 1, nxt = cur ^ 1;

        // ================= phase A: LSTM1 =================
        {
            // stage h1-region of x (fp16 pairs) into LDS via coherent u64 loads
            const ull* xsrc = xg64[cur];
            for (int i = tid; i < 4096; i += 512) {
                int bl = i >> 7, qp = i & 127;
                ull d = cld64(&xsrc[(bt * 32 + bl) * 128 + qp]);
                uint2 u; __builtin_memcpy(&u, &d, 8);
                *(uint2*)&xL[bl * 322 + 64 + qp * 2] = u;
            }
            // ctx merge (1 job per thread)
            {
                int bl = tid >> 4, q = tid & 15, b = bt * 32 + bl;
                unsigned* dst = &xL[bl * 322 + q * 4];
                float* hdst = (jt == 0 && l > 0)
                    ? &h2ctx[((size_t)b * LL + (l - 1)) * 256 + 128 + q * 8] : nullptr;
                ctx_merge_write(wc64, wms64, dst, hdst, b, q);
            }
            __syncthreads();

            const int j = tid >> 5, bl = tid & 31;
            const int b = bt * 32 + bl;
            const int g = j >> 2, hh = j & 3;
            const int jrow = g * 512 + jt * 4 + hh;
            const __half* EGh = (const __half*)EG;
            float acc = __half2float(EGh[((size_t)l * 2048 + jrow) * 64 + b]);
            const unsigned* wr = &w1L[j * 320];
            const unsigned* xr = &xL[bl * 322];
#pragma unroll 8
            for (int kp = 0; kp < 320; kp += 4) {
                uint4 wv = *(const uint4*)&wr[kp];
                uint2 x0 = *(const uint2*)&xr[kp];
                uint2 x1 = *(const uint2*)&xr[kp + 2];
                acc = dot2(wv.x, x0.x, acc); acc = dot2(wv.y, x0.y, acc);
                acc = dot2(wv.z, x1.x, acc); acc = dot2(wv.w, x1.y, acc);
            }
            redA[j * 32 + bl] = acc;
            __syncthreads();
            if (tid < 128) {
                int hh2 = tid >> 5, bl2 = tid & 31, b2 = bt * 32 + bl2;
                float g0 = redA[(0 * 4 + hh2) * 32 + bl2];
                float g1 = redA[(1 * 4 + hh2) * 32 + bl2];
                float g2 = redA[(2 * 4 + hh2) * 32 + bl2];
                float g3 = redA[(3 * 4 + hh2) * 32 + bl2];
                float iv = sigm(g0), fv = sigm(g1), gv = tanhf(g2), ov = sigm(g3);
                c1 = fv * c1 + iv * gv;
                float h1v = ov * tanhf(c1);
                float hp = __shfl_xor(h1v, 32);
                if (!(hh2 & 1))
                    cst32(&xg32[nxt][b2 * 256 + jt * 2 + (hh2 >> 1)], pk(h1v, hp));
            }
        }
        ++bk; gridbar(bar, bk, blk);

        // ================= phase B: LSTM2 (blk>=192) =================
        if (isB) {
            {
                const ull* xsrc = xg64[nxt];
                for (int i = tid; i < 1024; i += 512) {
                    int bli = i >> 7, qp = i & 127;
                    ull d = cld64(&xsrc[(bb0 + bli) * 128 + qp]);
                    uint2 u; __builtin_memcpy(&u, &d, 8);
                    *(uint2*)&xBL[bli * 322 + qp * 2] = u;
                }
            }
            if (tid < 256) {
                int bli = tid >> 5, qp = tid & 31;
                ull d = cld64(&h264[cur][(bb0 + bli) * 32 + qp]);
                uint2 u; __builtin_memcpy(&u, &d, 8);
                *(uint2*)&xBL[bli * 322 + 256 + qp * 2] = u;
            }
            __syncthreads();
            const int row = tid >> 3, bli = tid & 7;
            float acc = b2L[row];
            const unsigned* wr = &w2L[row * 324];
            const unsigned* xr = &xBL[bli * 322];
#pragma unroll 8
            for (int kp = 0; kp < 320; kp += 4) {
                uint4 wv = *(const uint4*)&wr[kp];
                uint2 x0 = *(const uint2*)&xr[kp];
                uint2 x1 = *(const uint2*)&xr[kp + 2];
                acc = dot2(wv.x, x0.x, acc); acc = dot2(wv.y, x0.y, acc);
                acc = dot2(wv.z, x1.x, acc); acc = dot2(wv.w, x1.y, acc);
            }
            red2[row * 8 + bli] = acc;
            __syncthreads();
            if (tid < 128) {
                int rr = tid >> 3, bli2 = tid & 7, b = bb0 + bli2;
                float g0 = red2[(0 * 16 + rr) * 8 + bli2];
                float g1 = red2[(1 * 16 + rr) * 8 + bli2];
                float g2 = red2[(2 * 16 + rr) * 8 + bli2];
                float g3 = red2[(3 * 16 + rr) * 8 + bli2];
                float iv = sigm(g0), fv = sigm(g1), gv = tanhf(g2), ov = sigm(g3);
                c2 = fv * c2 + iv * gv;
                float h2v = ov * tanhf(c2);
                h2ctx[((size_t)b * LL + l) * 256 + r0 + rr] = h2v;
                float hp = __shfl_xor(h2v, 8);
                if (!(rr & 1))
                    cst32(&h232[nxt][b * 64 + ((r0 + rr) >> 1)], pk(h2v, hp));
            }
        }
        ++bk; gridbar(bar, bk, blk);

        // ================= phase C: attention slice (blk<192) =================
        if (!isB) {
            if (tid < 32) {
                ull d = cld64(&h264[nxt][cb * 32 + tid]);
                uint2 u; __builtin_memcpy(&u, &d, 8);
                *(uint2*)&h2L[tid * 2] = u;
            }
            __syncthreads();
            const int tl = tid >> 1, ph = tid & 1;
            float e = 0.f;
            if (tl < TN) {
                const unsigned* kr = &keyL[tl * 70 + ph * 32];
                const int kb = ph * 32;
#pragma unroll 8
                for (int i = 0; i < 32; i += 2) {
                    uint2 kv = *(const uint2*)&kr[i];
                    e = dot2(kv.x, h2L[kb + i], e);
                    e = dot2(kv.y, h2L[kb + i + 1], e);
                }
            }
            if (tl < 168) ered[ph * 168 + tl] = e;
            __syncthreads();
            float me = -1e30f;
            if (tid < TN) {
                float et = ered[tid] + ered[168 + tid];
                me = (t0 + tid < len) ? et : 0.0f;
            }
            float mv = me;
#pragma unroll
            for (int s = 32; s; s >>= 1) mv = fmaxf(mv, __shfl_xor(mv, s));
            if ((tid & 63) == 0 && tid < 192) smx[tid >> 6] = mv;
            __syncthreads();
            const float m = fmaxf(smx[0], fmaxf(smx[1], smx[2]));
            float p = 0.f;
            if (tid < TN) p = __expf(me - m);
            float sv = p;
#pragma unroll
            for (int s = 32; s; s >>= 1) sv += __shfl_xor(sv, s);
            if ((tid & 63) == 0 && tid < 192) smx[4 + (tid >> 6)] = sv;
            if (tid < 168) {
                float pn = __shfl_xor(p, 1);
                if (!(tid & 1)) sph[tid >> 1] = pk(p, pn);
            }
            __syncthreads();
            const float sq = smx[4] + smx[5] + smx[6];
            // partial context over this slice
            const int v = tid & 127, tg = tid >> 7;
            float a = 0.f;
            const unsigned* vr = &valL[v * 85 + tg * 21];
            const unsigned* sr = &sph[tg * 21];
#pragma unroll 7
            for (int i = 0; i < 21; ++i) a = dot2(vr[i], sr[i], a);
            cred[tg * 128 + v] = a;
            __syncthreads();
            if (tid < 128) {
                float c = cred[tid] + cred[128 + tid] + cred[256 + tid] + cred[384 + tid];
                float cn = __shfl_xor(c, 1);
                if (!(tid & 1)) cst32(&wc32[(ts * 64 + cb) * 64 + (tid >> 1)], pk(c, cn));
                if (tid == 0) {
                    float2 msf = make_float2(m, sq);
                    ull v64; __builtin_memcpy(&v64, &msf, 8);
                    cst64(&wms64[ts * 64 + cb], v64);
                }
            }
        }
        ++bk; gridbar(bar, bk, blk);
    }

    // tail: ctx row for l=249
    if (jt == 0) {
        int bl = tid >> 4, q = tid & 15, b = bt * 32 + bl;
        ctx_merge_write(wc64, wms64, nullptr,
                        &h2ctx[((size_t)b * LL + (LL - 1)) * 256 + 128 + q * 8], b, q);
    }
}

// ---------------------------------------------------------------------------
extern "C" void kernel_launch(void* const* d_in, const int* in_sizes, int n_in,
                              void* d_out, int out_size, void* d_ws, size_t ws_size,
                              hipStream_t stream) {
    const float* key        = (const float*)d_in[0];
    const float* values     = (const float*)d_in[1];
    const int*   speech_len = (const int*)d_in[2];
    const int*   text       = (const int*)d_in[3];
    const float* embedding  = (const float*)d_in[4];
    const float* w_ih1 = (const float*)d_in[5];
    const float* b_ih1 = (const float*)d_in[6];
    const float* w_hh1 = (const float*)d_in[7];
    const float* b_hh1 = (const float*)d_in[8];
    const float* w_ih2 = (const float*)d_in[9];
    const float* b_ih2 = (const float*)d_in[10];
    const float* w_hh2 = (const float*)d_in[11];
    const float* b_hh2 = (const float*)d_in[12];
    const float* w_out = (const float*)d_in[13];
    const float* b_out = (const float*)d_in[14];
    float* out = (float*)d_out;

    float* ws    = (float*)d_ws;
    float* h2ctx = ws + WS_H2CTX;

    float* EmbW = out + OUT_EMBW;
    unsigned short* EG = (unsigned short*)(out + OUT_EG);
    unsigned* wp1  = (unsigned*)(out + OUT_WP1);
    unsigned* wp2  = (unsigned*)(out + OUT_WP2);
    unsigned* keyg = (unsigned*)(out + OUT_KEYG);
    unsigned* valg = (unsigned*)(out + OUT_VALG);

    (void)hipFuncSetAttribute((const void*)k_loop,
                              hipFuncAttributeMaxDynamicSharedMemorySize, LDS_BYTES);

    k_init<<<107, 512, 0, stream>>>(values, ws);
    k_pack<<<(PK_TOT + 511) / 512, 512, 0, stream>>>(key, values, w_ih1, w_hh1,
                                                     w_ih2, w_hh2, wp1, wp2, keyg, valg);
    // EmbW[v][j] = embedding[v] . w_ih1[j][:256] + b_ih1[j] + b_hh1[j]
    k_gemm_tn<<<dim3(32, 64), 256, 0, stream>>>(embedding, 256, w_ih1, 384,
                                                b_ih1, b_hh1, EmbW, 2048);
    k_eg<<<dim3(8, 250), 512, 0, stream>>>(text, EmbW, EG);
    k_loop<<<NBLK, 512, LDS_BYTES, stream>>>(speech_len, EG, wp1, wp2, keyg, valg,
                                             b_ih2, b_hh2, ws);
    // out[b*250+l][v] = h2ctx[b*250+l] . w_out[v] + b_out[v]
    k_gemm_tn<<<dim3(64, 250), 256, 0, stream>>>(h2ctx, 256, w_out, 256,
                                                 b_out, nullptr, out, 4096);
}

// Round 7
// 4745.251 us; speedup vs baseline: 11.3741x; 1.4161x over previous
//
#include <hip/hip_runtime.h>
#include <hip/hip_fp16.h>

#define LL 250
#define NBLK 256

typedef unsigned long long ull;

// ---- ws u32 offsets ----
#define WS_BAR    0        // 1024 (16 groups x 32)
#define WS_HG     1024     // [2][64 b][256] u32 fp16-pairs of h1
#define WS_H2G    33792    // [2][64 b][64] u32 fp16-pairs of h2
#define WS_WC     41984    // [4 ts][64 b][64 vp] u32 partial ctx
#define WS_WMS    58368    // [4][64][2] f32 (m,s)
#define WS_H2CTX  58880    // [64*250][256] f32
#define WS_INIT_END 58880

// ---- out scratch (float index units) ----
#define OUT_EMBW  0                 // 4096*2048 f32
#define OUT_EG    8388608           // EG2: 250*16*2048*2 u32 = 16,384,000 u32
#define OUT_WP1   25165824          // 2048*320 u32
#define OUT_WP2   25821184          // 512*320 u32
#define OUT_KEYG  25985024          // 64*500*64 u32
#define OUT_VALG  28033024          // 64*128*250 u32

// ---- k_loop LDS byte offsets ----
#define L_KEY  0                    // [126][68] u32 = 34272
#define L_VAL  34272                // [128][68] u32 = 34816
#define L_X    69088                // [4][328] u32 = 5248
#define L_G    74336                // 512 f32
#define L_E    76384                // 128 f32
#define L_SPH  76896                // 64 u32
#define L_MS   77152                // 8 f32
#define L_H2S  77184                // 64 u32
#define L_B2   77440                // 32 f32
#define LDS_BYTES 77568

__device__ __forceinline__ float sigm(float x) { return 1.0f / (1.0f + __expf(-x)); }

__device__ __forceinline__ unsigned pk(float a, float b) {
    __half2 h;
    h.x = __float2half_rn(a); h.y = __float2half_rn(b);
    unsigned u; __builtin_memcpy(&u, &h, 4); return u;
}
__device__ __forceinline__ float2 upk(unsigned u) {
    __half2 h; __builtin_memcpy(&h, &u, 4);
    return make_float2(__half2float(h.x), __half2float(h.y));
}

// coherent (agent-scope, L2-bypassing) exchange accessors
__device__ __forceinline__ ull cld64(const ull* p) {
    return __hip_atomic_load(p, __ATOMIC_RELAXED, __HIP_MEMORY_SCOPE_AGENT);
}
__device__ __forceinline__ unsigned cld32(const unsigned* p) {
    return __hip_atomic_load(p, __ATOMIC_RELAXED, __HIP_MEMORY_SCOPE_AGENT);
}
__device__ __forceinline__ void cst64(ull* p, ull v) {
    __hip_atomic_store(p, v, __ATOMIC_RELAXED, __HIP_MEMORY_SCOPE_AGENT);
}
__device__ __forceinline__ void cst32(unsigned* p, unsigned v) {
    __hip_atomic_store(p, v, __ATOMIC_RELAXED, __HIP_MEMORY_SCOPE_AGENT);
}

#ifndef __has_builtin
#define __has_builtin(x) 0
#endif
#if __has_builtin(__builtin_amdgcn_fdot2)
typedef _Float16 h2vec __attribute__((ext_vector_type(2)));
__device__ __forceinline__ float dot2(unsigned a, unsigned b, float c) {
    h2vec ha, hb;
    __builtin_memcpy(&ha, &a, 4); __builtin_memcpy(&hb, &b, 4);
    return __builtin_amdgcn_fdot2(ha, hb, c, false);
}
#else
__device__ __forceinline__ float dot2(unsigned a, unsigned b, float c) {
    float2 fa = upk(a), fb = upk(b);
    return c + fa.x * fb.x + fa.y * fb.y;
}
#endif

// ---------------------------------------------------------------------------
__global__ __launch_bounds__(512) void k_init(const float* __restrict__ values,
                                              float* __restrict__ ws) {
    int i = blockIdx.x * 512 + threadIdx.x;
    if (i >= WS_INIT_END) return;
    unsigned* wsu = (unsigned*)ws;
    if (i >= WS_WC && i < WS_WC + 4096) {          // wc[0][bg][vp] = values[t=0]
        int r = i - WS_WC, bg = r >> 6, vp = r & 63;
        wsu[i] = pk(values[bg * 128 + 2 * vp], values[bg * 128 + 2 * vp + 1]);
    } else if (i >= WS_WMS) {
        int r = i - WS_WMS;                        // [4][64][2]: slice0 (m=0,s=1)
        ws[i] = (((r >> 7) == 0) && (r & 1)) ? 1.0f : 0.0f;
    } else {
        ws[i] = 0.0f;
    }
}

// ---------------------------------------------------------------------------
// pack weights/key/values to fp16 pairs (layouts unchanged from R6)
// ---------------------------------------------------------------------------
#define PK_W1 655360
#define PK_W2 819200
#define PK_KEY 2867200
#define PK_TOT 4915200
__global__ __launch_bounds__(512) void k_pack(
        const float* __restrict__ key, const float* __restrict__ values,
        const float* __restrict__ w_ih1, const float* __restrict__ w_hh1,
        const float* __restrict__ w_ih2, const float* __restrict__ w_hh2,
        unsigned* __restrict__ wp1, unsigned* __restrict__ wp2,
        unsigned* __restrict__ keyg, unsigned* __restrict__ valg) {
    int idx = blockIdx.x * 512 + threadIdx.x;
    if (idx >= PK_TOT) return;
    if (idx < PK_W1) {
        int j = idx / 320, kp = idx % 320, k0 = 2 * kp;
        float a, b;
        if (k0 < 128) { a = w_ih1[j * 384 + 256 + k0]; b = w_ih1[j * 384 + 257 + k0]; }
        else          { a = w_hh1[j * 512 + k0 - 128]; b = w_hh1[j * 512 + k0 - 127]; }
        wp1[idx] = pk(a, b);
    } else if (idx < PK_W2) {
        int i2 = idx - PK_W1;
        int j = i2 / 320, kp = i2 % 320, k0 = 2 * kp;
        float a, b;
        if (k0 < 512) { a = w_ih2[j * 512 + k0]; b = w_ih2[j * 512 + k0 + 1]; }
        else          { a = w_hh2[j * 128 + k0 - 512]; b = w_hh2[j * 128 + k0 - 511]; }
        wp2[i2] = pk(a, b);
    } else if (idx < PK_KEY) {
        int i2 = idx - PK_W2;
        int b = i2 / 32000, r = i2 % 32000, t = r >> 6, kp = r & 63;
        const float* kr = key + ((size_t)t * 64 + b) * 128 + 2 * kp;
        keyg[i2] = pk(kr[0], kr[1]);
    } else {
        int i2 = idx - PK_KEY;
        int b = i2 / 32000, r = i2 % 32000, tp = r >> 7, v = r & 127;
        valg[b * 32000 + v * 250 + tp] =
            pk(values[((size_t)(2 * tp) * 64 + b) * 128 + v],
               values[((size_t)(2 * tp + 1) * 64 + b) * 128 + v]);
    }
}

// ---------------------------------------------------------------------------
// EG2[l][g][j] = uint2{ pk(EmbW[tok(4g)][j],   EmbW[tok(4g+1)][j]),
//                       pk(EmbW[tok(4g+2)][j], EmbW[tok(4g+3)][j]) }
// ---------------------------------------------------------------------------
__global__ __launch_bounds__(512) void k_eg2(const int* __restrict__ text,
                                             const float* __restrict__ EmbW,
                                             unsigned* __restrict__ EG2u) {
    const int jc = blockIdx.x, l = blockIdx.y;
    const int tid = threadIdx.x;
    __shared__ int tokL[64];
    if (tid < 64) tokL[tid] = (l == 0) ? 0 : text[tid * LL + l - 1];
    __syncthreads();
    const int j = jc * 256 + (tid & 255);
    const int half = tid >> 8;
    for (int gi = 0; gi < 8; ++gi) {
        int g = half * 8 + gi;
        float a0 = EmbW[(size_t)tokL[4 * g + 0] * 2048 + j];
        float a1 = EmbW[(size_t)tokL[4 * g + 1] * 2048 + j];
        float a2 = EmbW[(size_t)tokL[4 * g + 2] * 2048 + j];
        float a3 = EmbW[(size_t)tokL[4 * g + 3] * 2048 + j];
        uint2 u = make_uint2(pk(a0, a1), pk(a2, a3));
        *(uint2*)&EG2u[((size_t)(l * 16 + g) * 2048 + j) * 2] = u;
    }
}

// ---------------------------------------------------------------------------
// fp32 GEMM (K=256) — EmbW precompute and final projection
// ---------------------------------------------------------------------------
__global__ __launch_bounds__(256) void k_gemm_tn(
        const float* __restrict__ A, int lda,
        const float* __restrict__ B, int ldb,
        const float* __restrict__ bias1, const float* __restrict__ bias2,
        float* __restrict__ C, int ldc) {
    const int tid = threadIdx.x;
    const int m0 = blockIdx.y * 64, n0 = blockIdx.x * 64;
    const int tx = tid & 15, ty = tid >> 4;
    const int lm = tid >> 2, lk = (tid & 3) * 8;
    __shared__ float As[32][68];
    __shared__ float Bs[32][68];
    float c[4][4] = {{0.f}};
    for (int kb = 0; kb < 256; kb += 32) {
        const float* ap = A + (size_t)(m0 + lm) * lda + kb + lk;
        const float* bp = B + (size_t)(n0 + lm) * ldb + kb + lk;
        float4 a0 = *(const float4*)(ap);
        float4 a1 = *(const float4*)(ap + 4);
        float4 b0 = *(const float4*)(bp);
        float4 b1 = *(const float4*)(bp + 4);
        __syncthreads();
        As[lk + 0][lm] = a0.x; As[lk + 1][lm] = a0.y; As[lk + 2][lm] = a0.z; As[lk + 3][lm] = a0.w;
        As[lk + 4][lm] = a1.x; As[lk + 5][lm] = a1.y; As[lk + 6][lm] = a1.z; As[lk + 7][lm] = a1.w;
        Bs[lk + 0][lm] = b0.x; Bs[lk + 1][lm] = b0.y; Bs[lk + 2][lm] = b0.z; Bs[lk + 3][lm] = b0.w;
        Bs[lk + 4][lm] = b1.x; Bs[lk + 5][lm] = b1.y; Bs[lk + 6][lm] = b1.z; Bs[lk + 7][lm] = b1.w;
        __syncthreads();
#pragma unroll
        for (int kk = 0; kk < 32; ++kk) {
            const float4 a = *(const float4*)&As[kk][ty * 4];
            const float4 b = *(const float4*)&Bs[kk][tx * 4];
            c[0][0] += a.x * b.x; c[0][1] += a.x * b.y; c[0][2] += a.x * b.z; c[0][3] += a.x * b.w;
            c[1][0] += a.y * b.x; c[1][1] += a.y * b.y; c[1][2] += a.y * b.z; c[1][3] += a.y * b.w;
            c[2][0] += a.z * b.x; c[2][1] += a.z * b.y; c[2][2] += a.z * b.z; c[2][3] += a.z * b.w;
            c[3][0] += a.w * b.x; c[3][1] += a.w * b.y; c[3][2] += a.w * b.z; c[3][3] += a.w * b.w;
        }
    }
    const int n = n0 + tx * 4;
    float4 bb = *(const float4*)&bias1[n];
    if (bias2) {
        float4 b2 = *(const float4*)&bias2[n];
        bb.x += b2.x; bb.y += b2.y; bb.z += b2.z; bb.w += b2.w;
    }
#pragma unroll
    for (int i = 0; i < 4; ++i) {
        float4 r;
        r.x = c[i][0] + bb.x; r.y = c[i][1] + bb.y; r.z = c[i][2] + bb.z; r.w = c[i][3] + bb.w;
        *(float4*)&C[(size_t)(m0 + ty * 4 + i) * ldc + n] = r;
    }
}

// ---------------------------------------------------------------------------
// group sync: 16 blocks, monotonic counter per group, fence-free (sc exchange)
// ---------------------------------------------------------------------------
__device__ __forceinline__ void groupsync(unsigned* bar, int g, unsigned bk) {
    __syncthreads();
    if (threadIdx.x == 0) {
        unsigned* cnt = bar + g * 32;
        unsigned* gen = bar + g * 32 + 16;
        unsigned a = __hip_atomic_fetch_add(cnt, 1u, __ATOMIC_RELAXED, __HIP_MEMORY_SCOPE_AGENT);
        if (a == bk * 16u - 1u)
            __hip_atomic_store(gen, bk, __ATOMIC_RELAXED, __HIP_MEMORY_SCOPE_AGENT);
        while (__hip_atomic_load(gen, __ATOMIC_RELAXED, __HIP_MEMORY_SCOPE_AGENT) < bk)
            __builtin_amdgcn_s_sleep(1);
    }
    __syncthreads();
}

// exact 4-slice merge: ctx-pair for (bgs, vp)
__device__ __forceinline__ void ctx_merge(const unsigned* __restrict__ wc32,
                                          const ull* __restrict__ wmsU,
                                          int bgs, int vp, float* cx, float* cy) {
    float m[4], sv[4];
#pragma unroll
    for (int q = 0; q < 4; ++q) {
        ull v = cld64(&wmsU[q * 64 + bgs]);
        float2 f; __builtin_memcpy(&f, &v, 8);
        m[q] = f.x; sv[q] = f.y;
    }
    float M = fmaxf(fmaxf(m[0], m[1]), fmaxf(m[2], m[3]));
    float w[4];
    float den = 0.f;
#pragma unroll
    for (int q = 0; q < 4; ++q) { w[q] = __expf(m[q] - M); den += w[q] * sv[q]; }
    float inv = 1.0f / den;
    float x = 0.f, y = 0.f;
#pragma unroll
    for (int q = 0; q < 4; ++q) {
        float2 f = upk(cld32(&wc32[q * 4096 + bgs * 64 + vp]));
        x += w[q] * f.x; y += w[q] * f.y;
    }
    *cx = x * inv; *cy = y * inv;
}

// ---------------------------------------------------------------------------
// Persistent kernel: 16 groups x 16 blocks; group owns 4 batch elems.
// Per step: S1 LSTM1 (128 gate-rows x 4b, w1 streamed from L2) | sync |
//           S2 LSTM2 (32 gate-rows x 4b) | sync |
//           S3 attention slice (1 b, quarter of T, key/val LDS-pinned) | sync.
// No grid barrier; cross-block state via sc-coherent atomics (group-local).
// ---------------------------------------------------------------------------
__global__ __launch_bounds__(512) void k_loop(
        const int* __restrict__ speech_len,
        const unsigned* __restrict__ EG2u,
        const unsigned* __restrict__ wp1, const unsigned* __restrict__ wp2,
        const unsigned* __restrict__ keyg, const unsigned* __restrict__ valg,
        const float* __restrict__ b_ih2, const float* __restrict__ b_hh2,
        float* __restrict__ ws) {
    extern __shared__ char smem[];
    const int blk = blockIdx.x;
    const int tid = threadIdx.x;
    const int g = blk >> 4, s = blk & 15;

    unsigned* wsu = (unsigned*)ws;
    unsigned* bar   = wsu + WS_BAR;
    ull*      hgU   = (ull*)(wsu + WS_HG);     // [2][64][128]
    unsigned* hg32  = wsu + WS_HG;             // [2][64][256]
    ull*      h2gU  = (ull*)(wsu + WS_H2G);    // [2][64][32]
    unsigned* h2g32 = wsu + WS_H2G;            // [2][64][64]
    unsigned* wc32  = wsu + WS_WC;             // [4][64][64]
    ull*      wmsU  = (ull*)(wsu + WS_WMS);    // [4][64]
    float*    h2ctx = ws + WS_H2CTX;

    unsigned* keyL = (unsigned*)(smem + L_KEY);   // [126][68]
    unsigned* valL = (unsigned*)(smem + L_VAL);   // [128][68]
    unsigned* xL   = (unsigned*)(smem + L_X);     // [4][328]
    float*    gS   = (float*)(smem + L_G);        // [512]
    float*    eS   = (float*)(smem + L_E);        // [128]
    unsigned* sph  = (unsigned*)(smem + L_SPH);   // [64]
    float*    msS  = (float*)(smem + L_MS);       // [8]
    unsigned* h2S  = (unsigned*)(smem + L_H2S);   // [64]
    float*    b2S  = (float*)(smem + L_B2);       // [32]

    // attention slice geometry
    const int bl_att = s & 3, tsl = s >> 2;
    const int b_att = 4 * g + bl_att;
    const int pn  = (tsl < 2) ? 63 : 62;
    const int pp0 = (tsl < 2) ? 63 * tsl : 126 + 62 * (tsl - 2);
    const int t0 = 2 * pp0, tn = 2 * pn;

    // ---- prologue: key/val slices to LDS, lstm2 bias ----
    for (int i = tid; i < tn * 64; i += 512) {
        int tl = i >> 6, kp = i & 63;
        keyL[tl * 68 + kp] = keyg[(size_t)b_att * 32000 + (size_t)(t0 + tl) * 64 + kp];
    }
    for (int i = tid; i < 128 * 64; i += 512) {
        int v = i >> 6, pp = i & 63;
        valL[v * 68 + pp] = (pp < pn)
            ? valg[(size_t)b_att * 32000 + v * 250 + pp0 + pp] : 0u;
    }
    if (tid < 32) {
        int j2 = (tid >> 3) * 128 + s * 8 + (tid & 7);
        b2S[tid] = b_ih2[j2] + b_hh2[j2];
    }
    const int len_att = speech_len[b_att];
    __syncthreads();

    float c1 = 0.f, c2 = 0.f;
    unsigned bk = 0;

    for (int l = 0; l < LL; ++l) {
        const int cur = l & 1, nxt = cur ^ 1;

        // ================= S1: LSTM1 =================
        {   // stage h1(prev) into xL[bl][64..320)
            int bl = tid >> 7, qp = tid & 127;
            ull d = cld64(&hgU[(size_t)cur * 8192 + (4 * g + bl) * 128 + qp]);
            uint2 u; __builtin_memcpy(&u, &d, 8);
            *(uint2*)&xL[bl * 328 + 64 + 2 * qp] = u;
        }
        if (tid < 256) {  // ctx merge into xL[bl][0..64) (+ h2ctx row l-1 by s==0)
            int bl = tid & 3, vp = tid >> 2;
            int bgs = 4 * g + bl;
            float cx, cy;
            ctx_merge(wc32, wmsU, bgs, vp, &cx, &cy);
            xL[bl * 328 + vp] = pk(cx, cy);
            if (s == 0 && l > 0) {
                float* hd = &h2ctx[((size_t)bgs * LL + (l - 1)) * 256 + 128 + 2 * vp];
                hd[0] = cx; hd[1] = cy;
            }
        }
        __syncthreads();
        {   // gates: thread = (row_local rl, bl)
            int rl = tid >> 2, bl = tid & 3;
            int q = rl >> 5, hl = rl & 31;
            int j = q * 512 + s * 32 + hl;
            float2 eg = upk(EG2u[((size_t)(l * 16 + g) * 2048 + j) * 2 + (bl >> 1)]);
            float acc = (bl & 1) ? eg.y : eg.x;
            const uint4* wp = (const uint4*)(wp1 + (size_t)j * 320);
            const unsigned* xb = &xL[bl * 328];
#pragma unroll 8
            for (int it = 0; it < 80; ++it) {
                uint4 wv = wp[it];
                uint4 xv = *(const uint4*)&xb[it * 4];
                acc = dot2(wv.x, xv.x, acc); acc = dot2(wv.y, xv.y, acc);
                acc = dot2(wv.z, xv.z, acc); acc = dot2(wv.w, xv.w, acc);
            }
            gS[tid] = acc;
        }
        __syncthreads();
        if (tid < 128) {
            int hl = tid >> 2, bl = tid & 3;
            float g0 = gS[tid], g1 = gS[128 + tid], g2 = gS[256 + tid], g3 = gS[384 + tid];
            float iv = sigm(g0), fv = sigm(g1), gv = tanhf(g2), ov = sigm(g3);
            c1 = fv * c1 + iv * gv;
            float h1v = ov * tanhf(c1);
            float hp = __shfl_xor(h1v, 4);
            if (!(hl & 1))
                cst32(&hg32[nxt * 16384 + (4 * g + bl) * 256 + s * 16 + (hl >> 1)],
                      pk(h1v, hp));
        }
        ++bk; groupsync(bar, g, bk);

        // ================= S2: LSTM2 =================
        {   // stage full h1 into xL[bl][0..256)
            int bl = tid >> 7, qp = tid & 127;
            ull d = cld64(&hgU[(size_t)nxt * 8192 + (4 * g + bl) * 128 + qp]);
            uint2 u; __builtin_memcpy(&u, &d, 8);
            *(uint2*)&xL[bl * 328 + 2 * qp] = u;
        }
        if (tid < 128) {  // h2 prev into xL[bl][256..320)
            int bl = tid >> 5, qp = tid & 31;
            ull d = cld64(&h2gU[(size_t)cur * 2048 + (4 * g + bl) * 32 + qp]);
            uint2 u; __builtin_memcpy(&u, &d, 8);
            *(uint2*)&xL[bl * 328 + 256 + 2 * qp] = u;
        }
        __syncthreads();
        {
            int job = tid >> 2, ks = tid & 3;
            int rl2 = job >> 2, bl = job & 3;
            int j2 = (rl2 >> 3) * 128 + s * 8 + (rl2 & 7);
            float acc = (ks == 0) ? b2S[rl2] : 0.f;
            const uint4* wp = (const uint4*)(wp2 + (size_t)j2 * 320) + ks * 20;
            const unsigned* xb = &xL[bl * 328 + ks * 80];
#pragma unroll 5
            for (int it = 0; it < 20; ++it) {
                uint4 wv = wp[it];
                uint4 xv = *(const uint4*)&xb[it * 4];
                acc = dot2(wv.x, xv.x, acc); acc = dot2(wv.y, xv.y, acc);
                acc = dot2(wv.z, xv.z, acc); acc = dot2(wv.w, xv.w, acc);
            }
            acc += __shfl_xor(acc, 1);
            acc += __shfl_xor(acc, 2);
            if (ks == 0) gS[job] = acc;
        }
        __syncthreads();
        if (tid < 32) {
            int rl = tid >> 2, bl = tid & 3;
            float g0 = gS[tid], g1 = gS[32 + tid], g2 = gS[64 + tid], g3 = gS[96 + tid];
            float iv = sigm(g0), fv = sigm(g1), gv = tanhf(g2), ov = sigm(g3);
            c2 = fv * c2 + iv * gv;
            float h2v = ov * tanhf(c2);
            h2ctx[((size_t)(4 * g + bl) * LL + l) * 256 + s * 8 + rl] = h2v;
            float hp = __shfl_xor(h2v, 4);
            if (!(rl & 1))
                cst32(&h2g32[nxt * 4096 + (4 * g + bl) * 64 + s * 4 + (rl >> 1)],
                      pk(h2v, hp));
        }
        ++bk; groupsync(bar, g, bk);

        // ================= S3: attention slice =================
        if (tid < 32) {
            ull d = cld64(&h2gU[(size_t)nxt * 2048 + b_att * 32 + tid]);
            uint2 u; __builtin_memcpy(&u, &d, 8);
            *(uint2*)&h2S[2 * tid] = u;
        }
        __syncthreads();
        {   // energies
            int tl = tid >> 2, ks = tid & 3;
            float e = 0.f;
            if (tl < tn) {
                const uint4* kr = (const uint4*)&keyL[tl * 68] + ks * 4;
                const uint4* hr = (const uint4*)&h2S[ks * 16];
#pragma unroll
                for (int it = 0; it < 4; ++it) {
                    uint4 kv = kr[it]; uint4 hv = hr[it];
                    e = dot2(kv.x, hv.x, e); e = dot2(kv.y, hv.y, e);
                    e = dot2(kv.z, hv.z, e); e = dot2(kv.w, hv.w, e);
                }
            }
            e += __shfl_xor(e, 1);
            e += __shfl_xor(e, 2);
            if (ks == 0 && tl < tn)
                eS[tl] = (t0 + tl < len_att) ? e : 0.0f;
        }
        __syncthreads();
        float att_m = 0.f, att_s = 0.f;
        {
            float me = -1e30f, p = 0.f;
            if (tid < 128) {
                me = (tid < tn) ? eS[tid] : -1e30f;
                float mv = me;
#pragma unroll
                for (int off = 32; off; off >>= 1) mv = fmaxf(mv, __shfl_xor(mv, off));
                if ((tid & 63) == 0) msS[tid >> 6] = mv;
            }
            __syncthreads();
            float m = fmaxf(msS[0], msS[1]);
            if (tid < 128) {
                p = (tid < tn) ? __expf(me - m) : 0.0f;
                float sv = p;
#pragma unroll
                for (int off = 32; off; off >>= 1) sv += __shfl_xor(sv, off);
                if ((tid & 63) == 0) msS[2 + (tid >> 6)] = sv;
                float pnb = __shfl_xor(p, 1);
                if (!(tid & 1)) sph[tid >> 1] = pk(p, pnb);
            }
            __syncthreads();
            att_m = m;
            att_s = msS[2] + msS[3];
        }
        {   // partial context
            int v = tid >> 2, th = tid & 3;
            float a = 0.f;
            const uint4* vr = (const uint4*)&valL[v * 68] + th * 4;
            const uint4* pr = (const uint4*)&sph[th * 16];
#pragma unroll
            for (int it = 0; it < 4; ++it) {
                uint4 vv = vr[it]; uint4 pv = pr[it];
                a = dot2(vv.x, pv.x, a); a = dot2(vv.y, pv.y, a);
                a = dot2(vv.z, pv.z, a); a = dot2(vv.w, pv.w, a);
            }
            a += __shfl_xor(a, 1);
            a += __shfl_xor(a, 2);
            float an = __shfl_xor(a, 4);
            if (th == 0 && !(v & 1))
                cst32(&wc32[tsl * 4096 + b_att * 64 + (v >> 1)], pk(a, an));
            if (tid == 0) {
                float2 msf = make_float2(att_m, att_s);
                ull v64; __builtin_memcpy(&v64, &msf, 8);
                cst64(&wmsU[tsl * 64 + b_att], v64);
            }
        }
        ++bk; groupsync(bar, g, bk);
    }

    // tail: ctx rows for l = 249
    if (s == 0 && tid < 256) {
        int bl = tid & 3, vp = tid >> 2;
        int bgs = 4 * g + bl;
        float cx, cy;
        ctx_merge(wc32, wmsU, bgs, vp, &cx, &cy);
        float* hd = &h2ctx[((size_t)bgs * LL + (LL - 1)) * 256 + 128 + 2 * vp];
        hd[0] = cx; hd[1] = cy;
    }
}

// ---------------------------------------------------------------------------
extern "C" void kernel_launch(void* const* d_in, const int* in_sizes, int n_in,
                              void* d_out, int out_size, void* d_ws, size_t ws_size,
                              hipStream_t stream) {
    const float* key        = (const float*)d_in[0];
    const float* values     = (const float*)d_in[1];
    const int*   speech_len = (const int*)d_in[2];
    const int*   text       = (const int*)d_in[3];
    const float* embedding  = (const float*)d_in[4];
    const float* w_ih1 = (const float*)d_in[5];
    const float* b_ih1 = (const float*)d_in[6];
    const float* w_hh1 = (const float*)d_in[7];
    const float* b_hh1 = (const float*)d_in[8];
    const float* w_ih2 = (const float*)d_in[9];
    const float* b_ih2 = (const float*)d_in[10];
    const float* w_hh2 = (const float*)d_in[11];
    const float* b_hh2 = (const float*)d_in[12];
    const float* w_out = (const float*)d_in[13];
    const float* b_out = (const float*)d_in[14];
    float* out = (float*)d_out;

    float* ws    = (float*)d_ws;
    float* h2ctx = ws + WS_H2CTX;

    float* EmbW = out + OUT_EMBW;
    unsigned* EG2u = (unsigned*)(out + OUT_EG);
    unsigned* wp1  = (unsigned*)(out + OUT_WP1);
    unsigned* wp2  = (unsigned*)(out + OUT_WP2);
    unsigned* keyg = (unsigned*)(out + OUT_KEYG);
    unsigned* valg = (unsigned*)(out + OUT_VALG);

    (void)hipFuncSetAttribute((const void*)k_loop,
                              hipFuncAttributeMaxDynamicSharedMemorySize, LDS_BYTES);

    k_init<<<115, 512, 0, stream>>>(values, ws);
    k_pack<<<(PK_TOT + 511) / 512, 512, 0, stream>>>(key, values, w_ih1, w_hh1,
                                                     w_ih2, w_hh2, wp1, wp2, keyg, valg);
    // EmbW[v][j] = embedding[v] . w_ih1[j][:256] + b_ih1[j] + b_hh1[j]
    k_gemm_tn<<<dim3(32, 64), 256, 0, stream>>>(embedding, 256, w_ih1, 384,
                                                b_ih1, b_hh1, EmbW, 2048);
    k_eg2<<<dim3(8, 250), 512, 0, stream>>>(text, EmbW, EG2u);
    k_loop<<<NBLK, 512, LDS_BYTES, stream>>>(speech_len, EG2u, wp1, wp2, keyg, valg,
                                             b_ih2, b_hh2, ws);
    // out[b*250+l][v] = h2ctx[b*250+l] . w_out[v] + b_out[v]
    k_gemm_tn<<<dim3(64, 250), 256, 0, stream>>>(h2ctx, 256, w_out, 256,
                                                 b_out, nullptr, out, 4096);
}